// Round 2
// baseline (2026.237 us; speedup 1.0000x reference)
//
#include <hip/hip_runtime.h>

// RGCN 2-layer + mean-pool + linear, MI355X.
// Pipeline: wtrans -> hist -> scan(x3) -> scatter ->
//           per layer: [root transform | rel transform (gridDim.y=3) | aggregate3]
//           -> fused pool+final.
// CSR rebuilt per call (ws re-poisoned). fp32 vector math (no fp32 MFMA on CDNA4).

#define THREADS 256

// ---------- transpose the 8 96x96 weight matrices into ws (row-major [j][k]) ----------
__global__ __launch_bounds__(256) void k_wtrans(
    const float* __restrict__ Wroot1, const float* __restrict__ Wrel1,
    const float* __restrict__ Wroot2, const float* __restrict__ Wrel2,
    float* __restrict__ Wt)
{
  int b = blockIdx.x;
  const float* src;
  if (b == 0)      src = Wroot1;
  else if (b <= 3) src = Wrel1 + (size_t)(b - 1) * 96 * 96;
  else if (b == 4) src = Wroot2;
  else             src = Wrel2 + (size_t)(b - 5) * 96 * 96;
  float* dst = Wt + (size_t)b * 96 * 96;
  for (int idx = threadIdx.x; idx < 96 * 96; idx += THREADS) {
    int k = idx / 96, j = idx % 96;
    dst[j * 96 + k] = src[idx];  // read coalesced; tiny one-time scatter write
  }
}

// ---------- histogram of edges into (rel, dst) buckets ----------
__global__ __launch_bounds__(256) void k_hist(
    const int* __restrict__ ei, const int* __restrict__ et,
    int* __restrict__ cnt, int E, int N)
{
  int e = blockIdx.x * THREADS + threadIdx.x;
  if (e >= E) return;
  int dst = ei[E + e];
  int r = et[e];
  atomicAdd(&cnt[r * N + dst], 1);
}

// ---------- 3-kernel scan (inclusive, in place) over padded bucket counts ----------
__global__ __launch_bounds__(256) void k_scan1(int* __restrict__ data, int* __restrict__ blockSums)
{
  __shared__ int sh[256];
  int tid = threadIdx.x;
  size_t base = (size_t)blockIdx.x * 1024 + (size_t)tid * 4;
  int4 v = *(const int4*)(data + base);
  int i0 = v.x, i1 = i0 + v.y, i2 = i1 + v.z, i3 = i2 + v.w;
  int tsum = i3;
  sh[tid] = tsum;
  __syncthreads();
  for (int off = 1; off < 256; off <<= 1) {
    int t = (tid >= off) ? sh[tid - off] : 0;
    __syncthreads();
    sh[tid] += t;
    __syncthreads();
  }
  int excl = sh[tid] - tsum;
  int4 o;
  o.x = i0 + excl; o.y = i1 + excl; o.z = i2 + excl; o.w = i3 + excl;
  *(int4*)(data + base) = o;
  if (tid == 255) blockSums[blockIdx.x] = sh[255];
}

__global__ __launch_bounds__(256) void k_scan2(const int* __restrict__ blockSums,
                                               int* __restrict__ blockOffs, int nb)
{
  __shared__ int sh[256];
  int tid = threadIdx.x;
  int v = (tid < nb) ? blockSums[tid] : 0;  // nb <= 256 (3N/1024 = 147 here)
  sh[tid] = v;
  __syncthreads();
  for (int off = 1; off < 256; off <<= 1) {
    int t = (tid >= off) ? sh[tid - off] : 0;
    __syncthreads();
    sh[tid] += t;
    __syncthreads();
  }
  blockOffs[tid] = sh[tid] - v;  // exclusive offsets of block sums
}

__global__ __launch_bounds__(256) void k_scan3(int* __restrict__ data, const int* __restrict__ blockOffs)
{
  int tid = threadIdx.x;
  size_t base = (size_t)blockIdx.x * 1024 + (size_t)tid * 4;
  int add = blockOffs[blockIdx.x];
  int4 v = *(const int4*)(data + base);
  v.x += add; v.y += add; v.z += add; v.w += add;
  *(int4*)(data + base) = v;
}

// ---------- scatter edge src ids into CSR payload ----------
__global__ __launch_bounds__(256) void k_scatter(
    const int* __restrict__ ei, const int* __restrict__ et,
    const int* __restrict__ offs, int* __restrict__ cursor,
    int* __restrict__ payload, int E, int N)
{
  int e = blockIdx.x * THREADS + threadIdx.x;
  if (e >= E) return;
  int src = ei[e];
  int dst = ei[E + e];
  int r = et[e];
  int bucket = r * N + dst;
  int base = (bucket == 0) ? 0 : offs[bucket - 1];
  int pos = base + atomicAdd(&cursor[bucket], 1);
  payload[pos] = src;
}

// ---------- dense transform: Y[y][N][96] = X[N][96] @ Wt[widx0+y] (+bias) ----------
// Wt pre-transposed ([outcol][k]); staged in LDS with float4-chunk XOR swizzle
// (chunk ^= outcol&7): per-column stride-384B reads spread over all 8 bank
// groups (4-way alias on distinct rows = b128 minimum cycles).
__global__ __launch_bounds__(256) void k_transform(
    const float* __restrict__ X, const float* __restrict__ WtBase, int widx0,
    const float* __restrict__ bias, float* __restrict__ Y, size_t ystride,
    int nRows)
{
  __shared__ float4 Wl[96 * 24];
  __shared__ float4 Xl[32 * 24];
  int tid = threadIdx.x;
  const float4* Wt4 = (const float4*)(WtBase + (size_t)(widx0 + blockIdx.y) * 96 * 96);
  for (int idx = tid; idx < 96 * 24; idx += THREADS) {
    int j = idx / 24, k4 = idx % 24;
    Wl[j * 24 + (k4 ^ (j & 7))] = Wt4[idx];
  }
  int r0 = blockIdx.x * 32;
  const float4* X4 = (const float4*)X;
  for (int idx = tid; idx < 32 * 24; idx += THREADS) {
    int row = idx / 24, k4 = idx % 24;
    int i = r0 + row;
    Xl[idx] = (i < nRows) ? X4[(size_t)i * 24 + k4] : make_float4(0.f, 0.f, 0.f, 0.f);
  }
  __syncthreads();

  int lane = tid & 31;       // output cols: lane, lane+32, lane+64
  int rowg = tid >> 5;       // 8 row groups x 4 rows
  float acc[4][3];
#pragma unroll
  for (int q = 0; q < 4; ++q)
#pragma unroll
    for (int c = 0; c < 3; ++c) acc[q][c] = 0.f;

  int kx = lane & 7;
  int wb0 = lane * 24, wb1 = (lane + 32) * 24, wb2 = (lane + 64) * 24;
#pragma unroll
  for (int k4 = 0; k4 < 24; ++k4) {
    int kw = k4 ^ kx;
    float4 w0 = Wl[wb0 + kw];
    float4 w1 = Wl[wb1 + kw];
    float4 w2 = Wl[wb2 + kw];
#pragma unroll
    for (int q = 0; q < 4; ++q) {
      float4 xv = Xl[(rowg * 4 + q) * 24 + k4];  // same-addr broadcast per half-wave
      acc[q][0] = fmaf(xv.x, w0.x, acc[q][0]);
      acc[q][0] = fmaf(xv.y, w0.y, acc[q][0]);
      acc[q][0] = fmaf(xv.z, w0.z, acc[q][0]);
      acc[q][0] = fmaf(xv.w, w0.w, acc[q][0]);
      acc[q][1] = fmaf(xv.x, w1.x, acc[q][1]);
      acc[q][1] = fmaf(xv.y, w1.y, acc[q][1]);
      acc[q][1] = fmaf(xv.z, w1.z, acc[q][1]);
      acc[q][1] = fmaf(xv.w, w1.w, acc[q][1]);
      acc[q][2] = fmaf(xv.x, w2.x, acc[q][2]);
      acc[q][2] = fmaf(xv.y, w2.y, acc[q][2]);
      acc[q][2] = fmaf(xv.z, w2.z, acc[q][2]);
      acc[q][2] = fmaf(xv.w, w2.w, acc[q][2]);
    }
  }

  float bb0 = 0.f, bb1 = 0.f, bb2 = 0.f;
  if (bias) { bb0 = bias[lane]; bb1 = bias[lane + 32]; bb2 = bias[lane + 64]; }
  float* Yb = Y + (size_t)blockIdx.y * ystride;
#pragma unroll
  for (int q = 0; q < 4; ++q) {
    int i = r0 + rowg * 4 + q;
    if (i < nRows) {
      float* yp = Yb + (size_t)i * 96;
      yp[lane]      = acc[q][0] + bb0;
      yp[lane + 32] = acc[q][1] + bb1;
      yp[lane + 64] = acc[q][2] + bb2;
    }
  }
}

// ---------- merged aggregate: R[i] += sum_r mean_{e in (r,i)} H3[r][src_e]; relu ----------
__global__ __launch_bounds__(256) void k_aggregate3(
    const float* __restrict__ H3, const int* __restrict__ offs,
    const int* __restrict__ payload, float* __restrict__ R,
    int nNodes)
{
  int hw = (blockIdx.x * THREADS + threadIdx.x) >> 5;  // half-wave per node
  int lane = threadIdx.x & 31;
  if (hw >= nNodes) return;
  float* rp = R + (size_t)hw * 96;
  float v0 = rp[lane], v1 = rp[lane + 32], v2 = rp[lane + 64];
#pragma unroll
  for (int r = 0; r < 3; ++r) {
    int bucket = r * nNodes + hw;
    int start = (bucket == 0) ? 0 : offs[bucket - 1];
    int end = offs[bucket];
    const float* H = H3 + (size_t)r * nNodes * 96;
    float a0 = 0.f, a1 = 0.f, a2 = 0.f;
    for (int e = start; e < end; ++e) {
      const float* hp = H + (size_t)payload[e] * 96;
      a0 += hp[lane];
      a1 += hp[lane + 32];
      a2 += hp[lane + 64];
    }
    float inv = (end > start) ? 1.0f / (float)(end - start) : 0.0f;
    v0 += a0 * inv; v1 += a1 * inv; v2 += a2 * inv;
  }
  rp[lane]      = fmaxf(v0, 0.f);
  rp[lane + 32] = fmaxf(v1, 0.f);
  rp[lane + 64] = fmaxf(v2, 0.f);
}

// ---------- single-relation fallback (small ws): R += mean; relu on last ----------
__global__ __launch_bounds__(256) void k_aggregate1(
    const float* __restrict__ H, const int* __restrict__ offs,
    const int* __restrict__ payload, float* __restrict__ R,
    int rbase, int finalize, int nNodes)
{
  int hw = (blockIdx.x * THREADS + threadIdx.x) >> 5;
  int lane = threadIdx.x & 31;
  if (hw >= nNodes) return;
  int bucket = rbase + hw;
  int start = (bucket == 0) ? 0 : offs[bucket - 1];
  int end = offs[bucket];
  float a0 = 0.f, a1 = 0.f, a2 = 0.f;
  for (int e = start; e < end; ++e) {
    const float* hp = H + (size_t)payload[e] * 96;
    a0 += hp[lane];
    a1 += hp[lane + 32];
    a2 += hp[lane + 64];
  }
  float inv = (end > start) ? 1.0f / (float)(end - start) : 0.0f;
  float* rp = R + (size_t)hw * 96;
  float v0 = rp[lane] + a0 * inv;
  float v1 = rp[lane + 32] + a1 * inv;
  float v2 = rp[lane + 64] + a2 * inv;
  if (finalize) { v0 = fmaxf(v0, 0.f); v1 = fmaxf(v1, 0.f); v2 = fmaxf(v2, 0.f); }
  rp[lane] = v0;
  rp[lane + 32] = v1;
  rp[lane + 64] = v2;
}

// ---------- fused: graph bounds (binary search) + mean pool + 96->16 linear ----------
__global__ __launch_bounds__(256) void k_poolfinal(
    const float* __restrict__ h, const int* __restrict__ batch,
    const float* __restrict__ Wlin, const float* __restrict__ blin,
    float* __restrict__ out, int N, int G)
{
  int g = (blockIdx.x * THREADS + threadIdx.x) >> 5;  // half-wave per graph
  int lane = threadIdx.x & 31;
  if (g >= G) return;
  // lower_bound(batch, g) and lower_bound(batch, g+1); batch is sorted
  int s, e;
  {
    int lo = 0, hi = N;
    while (lo < hi) { int mid = (lo + hi) >> 1; if (batch[mid] < g) lo = mid + 1; else hi = mid; }
    s = lo;
    hi = N;
    while (lo < hi) { int mid = (lo + hi) >> 1; if (batch[mid] < g + 1) lo = mid + 1; else hi = mid; }
    e = lo;
  }
  float a0 = 0.f, a1 = 0.f, a2 = 0.f;
  for (int i = s; i < e; ++i) {
    const float* hp = h + (size_t)i * 96;
    a0 += hp[lane];
    a1 += hp[lane + 32];
    a2 += hp[lane + 64];
  }
  float inv = (e > s) ? 1.0f / (float)(e - s) : 0.0f;
  a0 *= inv; a1 *= inv; a2 *= inv;
  // out[g][c] = sum_k pooled[k] * Wlin[k][c] + blin[c]; lane owns k in {lane, lane+32, lane+64}
#pragma unroll
  for (int c = 0; c < 16; ++c) {
    float t = a0 * Wlin[lane * 16 + c]
            + a1 * Wlin[(lane + 32) * 16 + c]
            + a2 * Wlin[(lane + 64) * 16 + c];
#pragma unroll
    for (int off = 16; off > 0; off >>= 1) t += __shfl_xor(t, off, 32);
    if (lane == 0) out[(size_t)g * 16 + c] = t + blin[c];
  }
}

extern "C" void kernel_launch(void* const* d_in, const int* in_sizes, int n_in,
                              void* d_out, int out_size, void* d_ws, size_t ws_size,
                              hipStream_t stream)
{
  const float* x      = (const float*)d_in[0];
  const int*   ei     = (const int*)d_in[1];
  const int*   et     = (const int*)d_in[2];
  const int*   batch  = (const int*)d_in[3];
  const float* Wrel1  = (const float*)d_in[4];
  const float* Wroot1 = (const float*)d_in[5];
  const float* b1     = (const float*)d_in[6];
  const float* Wrel2  = (const float*)d_in[7];
  const float* Wroot2 = (const float*)d_in[8];
  const float* b2     = (const float*)d_in[9];
  const float* Wlin   = (const float*)d_in[10];
  const float* blin   = (const float*)d_in[11];
  float* out = (float*)d_out;
  (void)n_in;

  int N = in_sizes[0] / 96;
  int E = in_sizes[1] / 2;
  int G = out_size / 16;
  int NB = 3 * N;
  int nb1 = (NB + 1023) / 1024;      // scan blocks, <=256 (147 here)
  int SCAN = nb1 * 1024;

  size_t nodeBytes = (size_t)N * 96 * 4;
  size_t fixed = (size_t)8 * 96 * 96 * 4 + (size_t)SCAN * 4 * 2 + 512 * 4 * 2
               + (size_t)E * 4 + (size_t)4096;  // Wt, offs+cursor, scan temps, payload, align slack
  bool merged = ws_size >= fixed + 5 * nodeBytes;   // H3(3) + R1 + R2
  int nH = merged ? 3 : 1;

  char* w = (char*)d_ws;
  size_t o = 0;
  auto carve = [&](size_t bytes) -> char* {
    char* p = w + o;
    o = (o + bytes + 255) & ~(size_t)255;
    return p;
  };
  float* H3       = (float*)carve(nodeBytes * nH);
  float* R1       = (float*)carve(nodeBytes);
  float* R2       = (float*)carve(nodeBytes);
  float* Wt       = (float*)carve((size_t)8 * 96 * 96 * 4);
  int*   offs     = (int*)carve((size_t)SCAN * 4);
  int*   blockSums= (int*)carve(256 * 4);
  int*   blockOffs= (int*)carve(256 * 4);
  int*   cursor   = (int*)carve((size_t)SCAN * 4);
  int*   payload  = (int*)carve((size_t)E * 4);

  hipMemsetAsync(offs, 0, (size_t)SCAN * 4, stream);
  hipMemsetAsync(cursor, 0, (size_t)SCAN * 4, stream);

  k_wtrans<<<8, THREADS, 0, stream>>>(Wroot1, Wrel1, Wroot2, Wrel2, Wt);
  k_hist<<<(E + THREADS - 1) / THREADS, THREADS, 0, stream>>>(ei, et, offs, E, N);
  k_scan1<<<nb1, THREADS, 0, stream>>>(offs, blockSums);
  k_scan2<<<1, THREADS, 0, stream>>>(blockSums, blockOffs, nb1);
  k_scan3<<<nb1, THREADS, 0, stream>>>(offs, blockOffs);
  k_scatter<<<(E + THREADS - 1) / THREADS, THREADS, 0, stream>>>(ei, et, offs, cursor, payload, E, N);

  dim3 tg1((N + 31) / 32, 1), tg3((N + 31) / 32, 3);
  int ag = (N + 7) / 8;

  if (merged) {
    // layer 1
    k_transform<<<tg1, THREADS, 0, stream>>>(x, Wt, 0, b1, R1, 0, N);
    k_transform<<<tg3, THREADS, 0, stream>>>(x, Wt, 1, nullptr, H3, nodeBytes / 4, N);
    k_aggregate3<<<ag, THREADS, 0, stream>>>(H3, offs, payload, R1, N);
    // layer 2
    k_transform<<<tg1, THREADS, 0, stream>>>(R1, Wt, 4, b2, R2, 0, N);
    k_transform<<<tg3, THREADS, 0, stream>>>(R1, Wt, 5, nullptr, H3, nodeBytes / 4, N);
    k_aggregate3<<<ag, THREADS, 0, stream>>>(H3, offs, payload, R2, N);
  } else {
    k_transform<<<tg1, THREADS, 0, stream>>>(x, Wt, 0, b1, R1, 0, N);
    for (int r = 0; r < 3; ++r) {
      k_transform<<<tg1, THREADS, 0, stream>>>(x, Wt, 1 + r, nullptr, H3, 0, N);
      k_aggregate1<<<ag, THREADS, 0, stream>>>(H3, offs, payload, R1, r * N, (r == 2) ? 1 : 0, N);
    }
    k_transform<<<tg1, THREADS, 0, stream>>>(R1, Wt, 4, b2, R2, 0, N);
    for (int r = 0; r < 3; ++r) {
      k_transform<<<tg1, THREADS, 0, stream>>>(R1, Wt, 5 + r, nullptr, H3, 0, N);
      k_aggregate1<<<ag, THREADS, 0, stream>>>(H3, offs, payload, R2, r * N, (r == 2) ? 1 : 0, N);
    }
  }

  k_poolfinal<<<(G * 32 + THREADS - 1) / THREADS, THREADS, 0, stream>>>(
      R2, batch, Wlin, blin, out, N, G);
}

// Round 3
// 411.024 us; speedup vs baseline: 4.9297x; 4.9297x over previous
//
#include <hip/hip_runtime.h>

// RGCN 2-layer + mean-pool + linear, MI355X (gfx950).
// This round: dense transforms moved to bf16 MFMA (16x16x32) with split-bf16
// (hi/lo) operands for ~fp32 accuracy. One GEMM per layer computes
// Y[N][384] = X[N][96] @ [Wroot | Wrel0 | Wrel1 | Wrel2]  (fp32 accum/out).
// B is pre-packed in MFMA fragment order -> GEMM uses no LDS; A frags are
// 16B/lane loads from a bf16 copy of X. Bias+relu+per-relation means fold
// into the aggregate kernel, which also emits the next layer's bf16 input.

#define THREADS 256

typedef __attribute__((ext_vector_type(8))) short short8v;   // 8 x bf16 (4 VGPRs)
typedef __attribute__((ext_vector_type(4))) float f32x4;

__device__ __forceinline__ unsigned short f2bf(float f) {
  union { float f; unsigned u; } v; v.f = f;
  unsigned r = v.u + 0x7FFF + ((v.u >> 16) & 1);   // RNE
  return (unsigned short)(r >> 16);
}
__device__ __forceinline__ float bf2f(unsigned short b) {
  union { unsigned u; float f; } v; v.u = ((unsigned)b) << 16;
  return v.f;
}

// ---------- pack W (both layers) into MFMA B-fragment order, split hi/lo ----------
// Fragment addr: idx = ((ks*24 + CT)*64 + lane)*8 + j  maps to
//   B[k = ks*32 + (lane>>4)*8 + j][col = CT*16 + (lane&15)]
__global__ __launch_bounds__(256) void k_packW(
    const float* __restrict__ Wrel1, const float* __restrict__ Wroot1,
    const float* __restrict__ Wrel2, const float* __restrict__ Wroot2,
    unsigned short* __restrict__ PBh, unsigned short* __restrict__ PBl)
{
  int lay = blockIdx.x;
  const float* Wroot = lay ? Wroot2 : Wroot1;
  const float* Wrel  = lay ? Wrel2  : Wrel1;
  for (int idx = threadIdx.x; idx < 36864; idx += THREADS) {
    int j    = idx & 7;
    int lane = (idx >> 3) & 63;
    int CT   = (idx >> 9) % 24;
    int ks   = (idx >> 9) / 24;
    int k    = ks * 32 + (lane >> 4) * 8 + j;
    int col  = CT * 16 + (lane & 15);
    int m    = col / 96, jj = col % 96;
    float f  = (m == 0) ? Wroot[k * 96 + jj]
                        : Wrel[((size_t)(m - 1) * 96 + k) * 96 + jj];
    unsigned short h = f2bf(f);
    PBh[(size_t)lay * 36864 + idx] = h;
    PBl[(size_t)lay * 36864 + idx] = f2bf(f - bf2f(h));
  }
}

// ---------- convert fp32 features -> split bf16 (hi/lo), vectorized ----------
__global__ __launch_bounds__(256) void k_convX(
    const float4* __restrict__ X4, unsigned short* __restrict__ Xh,
    unsigned short* __restrict__ Xl, int n4)
{
  int i = blockIdx.x * THREADS + threadIdx.x;
  if (i >= n4) return;
  float4 v = X4[i];
  ushort4 h, l;
  h.x = f2bf(v.x); l.x = f2bf(v.x - bf2f(h.x));
  h.y = f2bf(v.y); l.y = f2bf(v.y - bf2f(h.y));
  h.z = f2bf(v.z); l.z = f2bf(v.z - bf2f(h.z));
  h.w = f2bf(v.w); l.w = f2bf(v.w - bf2f(h.w));
  *(ushort4*)(Xh + (size_t)i * 4) = h;
  *(ushort4*)(Xl + (size_t)i * 4) = l;
}

// ---------- CSR build: histogram -> scan(x3) -> scatter ----------
__global__ __launch_bounds__(256) void k_hist(
    const int* __restrict__ ei, const int* __restrict__ et,
    int* __restrict__ cnt, int E, int N)
{
  int e = blockIdx.x * THREADS + threadIdx.x;
  if (e >= E) return;
  atomicAdd(&cnt[et[e] * N + ei[E + e]], 1);
}

__global__ __launch_bounds__(256) void k_scan1(int* __restrict__ data, int* __restrict__ blockSums)
{
  __shared__ int sh[256];
  int tid = threadIdx.x;
  size_t base = (size_t)blockIdx.x * 1024 + (size_t)tid * 4;
  int4 v = *(const int4*)(data + base);
  int i0 = v.x, i1 = i0 + v.y, i2 = i1 + v.z, i3 = i2 + v.w;
  int tsum = i3;
  sh[tid] = tsum;
  __syncthreads();
  for (int off = 1; off < 256; off <<= 1) {
    int t = (tid >= off) ? sh[tid - off] : 0;
    __syncthreads();
    sh[tid] += t;
    __syncthreads();
  }
  int excl = sh[tid] - tsum;
  int4 o; o.x = i0 + excl; o.y = i1 + excl; o.z = i2 + excl; o.w = i3 + excl;
  *(int4*)(data + base) = o;
  if (tid == 255) blockSums[blockIdx.x] = sh[255];
}

__global__ __launch_bounds__(256) void k_scan2(const int* __restrict__ blockSums,
                                               int* __restrict__ blockOffs, int nb)
{
  __shared__ int sh[256];
  int tid = threadIdx.x;
  int v = (tid < nb) ? blockSums[tid] : 0;
  sh[tid] = v;
  __syncthreads();
  for (int off = 1; off < 256; off <<= 1) {
    int t = (tid >= off) ? sh[tid - off] : 0;
    __syncthreads();
    sh[tid] += t;
    __syncthreads();
  }
  blockOffs[tid] = sh[tid] - v;
}

__global__ __launch_bounds__(256) void k_scan3(int* __restrict__ data, const int* __restrict__ blockOffs)
{
  int tid = threadIdx.x;
  size_t base = (size_t)blockIdx.x * 1024 + (size_t)tid * 4;
  int add = blockOffs[blockIdx.x];
  int4 v = *(const int4*)(data + base);
  v.x += add; v.y += add; v.z += add; v.w += add;
  *(int4*)(data + base) = v;
}

__global__ __launch_bounds__(256) void k_scatter(
    const int* __restrict__ ei, const int* __restrict__ et,
    const int* __restrict__ offs, int* __restrict__ cursor,
    int* __restrict__ payload, int E, int N)
{
  int e = blockIdx.x * THREADS + threadIdx.x;
  if (e >= E) return;
  int bucket = et[e] * N + ei[E + e];
  int base = (bucket == 0) ? 0 : offs[bucket - 1];
  payload[base + atomicAdd(&cursor[bucket], 1)] = ei[e];
}

// ---------- MFMA GEMM: Y[N][384] = X[N][96] @ Bcat[96][384], split-bf16 ----------
// Block = 64 rows x 384 cols; wave w owns cols [w*96, w*96+96).
// acc[rt][ct]: rows r0+rt*16+(lane>>4)*4+q, col w*96+ct*16+(lane&15).
__global__ __launch_bounds__(256) void k_gemm(
    const unsigned short* __restrict__ Xh, const unsigned short* __restrict__ Xl,
    const unsigned short* __restrict__ PBh, const unsigned short* __restrict__ PBl,
    float* __restrict__ Y, int nRows)
{
  int wv = threadIdx.x >> 6, lane = threadIdx.x & 63;
  int lr = lane & 15, lq = lane >> 4;
  int r0 = blockIdx.x * 64;

  f32x4 acc[4][6];
#pragma unroll
  for (int rt = 0; rt < 4; ++rt)
#pragma unroll
    for (int ct = 0; ct < 6; ++ct) acc[rt][ct] = (f32x4){0.f, 0.f, 0.f, 0.f};

#pragma unroll 1
  for (int ks = 0; ks < 3; ++ks) {
    short8v Ah[4], Al[4];
#pragma unroll
    for (int rt = 0; rt < 4; ++rt) {
      int row = r0 + rt * 16 + lr;
      if (row >= nRows) row = nRows - 1;          // clamp; stores are guarded
      size_t off = (size_t)row * 96 + ks * 32 + lq * 8;
      Ah[rt] = *(const short8v*)(Xh + off);
      Al[rt] = *(const short8v*)(Xl + off);
    }
#pragma unroll
    for (int ct = 0; ct < 6; ++ct) {
      int CT = wv * 6 + ct;
      size_t boff = ((size_t)(ks * 24 + CT) * 64 + lane) * 8;
      short8v Bh = *(const short8v*)(PBh + boff);
      short8v Bl = *(const short8v*)(PBl + boff);
#pragma unroll
      for (int rt = 0; rt < 4; ++rt) {
        acc[rt][ct] = __builtin_amdgcn_mfma_f32_16x16x32_bf16(Ah[rt], Bh, acc[rt][ct], 0, 0, 0);
        acc[rt][ct] = __builtin_amdgcn_mfma_f32_16x16x32_bf16(Al[rt], Bh, acc[rt][ct], 0, 0, 0);
        acc[rt][ct] = __builtin_amdgcn_mfma_f32_16x16x32_bf16(Ah[rt], Bl, acc[rt][ct], 0, 0, 0);
      }
    }
  }

#pragma unroll
  for (int rt = 0; rt < 4; ++rt) {
#pragma unroll
    for (int q = 0; q < 4; ++q) {
      int row = r0 + rt * 16 + lq * 4 + q;
      if (row < nRows) {
        float* yp = Y + (size_t)row * 384 + wv * 96 + lr;
#pragma unroll
        for (int ct = 0; ct < 6; ++ct) yp[ct * 16] = acc[rt][ct][q];
      }
    }
  }
}

// ---------- aggregate: v = Yroot + bias + sum_r mean_r(gather); relu ----------
// Writes either split-bf16 (next layer's GEMM input) or fp32 in place.
__global__ __launch_bounds__(256) void k_agg3(
    const float* Y, const int* __restrict__ offs, const int* __restrict__ payload,
    const float* __restrict__ bias,
    unsigned short* outH, unsigned short* outL, float* outF, int nNodes)
{
  int hw = (blockIdx.x * THREADS + threadIdx.x) >> 5;
  int lane = threadIdx.x & 31;
  if (hw >= nNodes) return;
  const float* yp = Y + (size_t)hw * 384;
  float v0 = yp[lane]      + bias[lane];
  float v1 = yp[lane + 32] + bias[lane + 32];
  float v2 = yp[lane + 64] + bias[lane + 64];
#pragma unroll
  for (int r = 0; r < 3; ++r) {
    int bucket = r * nNodes + hw;
    int start = (bucket == 0) ? 0 : offs[bucket - 1];
    int end = offs[bucket];
    const float* base = Y + 96 + r * 96;
    float a0 = 0.f, a1 = 0.f, a2 = 0.f;
    for (int e = start; e < end; ++e) {
      const float* hp = base + (size_t)payload[e] * 384;
      a0 += hp[lane];
      a1 += hp[lane + 32];
      a2 += hp[lane + 64];
    }
    float inv = (end > start) ? 1.0f / (float)(end - start) : 0.0f;
    v0 += a0 * inv; v1 += a1 * inv; v2 += a2 * inv;
  }
  v0 = fmaxf(v0, 0.f); v1 = fmaxf(v1, 0.f); v2 = fmaxf(v2, 0.f);
  if (outF) {
    float* op = outF + (size_t)hw * 384;
    op[lane] = v0; op[lane + 32] = v1; op[lane + 64] = v2;
  } else {
    unsigned short h0 = f2bf(v0), h1 = f2bf(v1), h2 = f2bf(v2);
    size_t b = (size_t)hw * 96;
    outH[b + lane] = h0;      outL[b + lane]      = f2bf(v0 - bf2f(h0));
    outH[b + lane + 32] = h1; outL[b + lane + 32] = f2bf(v1 - bf2f(h1));
    outH[b + lane + 64] = h2; outL[b + lane + 64] = f2bf(v2 - bf2f(h2));
  }
}

// ---------- one block per graph: mean pool (stride-384 rows) + 96->16 linear ----------
__global__ __launch_bounds__(256) void k_poolfinal(
    const float* __restrict__ Y, const int* __restrict__ batch,
    const float* __restrict__ Wlin, const float* __restrict__ blin,
    float* __restrict__ out, int N, int G)
{
  int g = blockIdx.x;
  int tid = threadIdx.x;
  int lo = 0, hi = N;
  while (lo < hi) { int m = (lo + hi) >> 1; if (batch[m] < g) lo = m + 1; else hi = m; }
  int s = lo; hi = N;
  while (lo < hi) { int m = (lo + hi) >> 1; if (batch[m] < g + 1) lo = m + 1; else hi = m; }
  int e = lo;

  int hw = tid >> 5, lane = tid & 31;
  float a0 = 0.f, a1 = 0.f, a2 = 0.f;
  for (int i = s + hw; i < e; i += 8) {
    const float* hp = Y + (size_t)i * 384;
    a0 += hp[lane]; a1 += hp[lane + 32]; a2 += hp[lane + 64];
  }
  __shared__ float sh[8][96];
  __shared__ float pooled[96];
  sh[hw][lane] = a0; sh[hw][lane + 32] = a1; sh[hw][lane + 64] = a2;
  __syncthreads();
  if (tid < 96) {
    float t = 0.f;
#pragma unroll
    for (int j = 0; j < 8; ++j) t += sh[j][tid];
    float inv = (e > s) ? 1.0f / (float)(e - s) : 0.0f;
    pooled[tid] = t * inv;
  }
  __syncthreads();
  if (tid < 16) {
    float acc = blin[tid];
    for (int k = 0; k < 96; ++k) acc = fmaf(pooled[k], Wlin[k * 16 + tid], acc);
    out[(size_t)g * 16 + tid] = acc;
  }
}

extern "C" void kernel_launch(void* const* d_in, const int* in_sizes, int n_in,
                              void* d_out, int out_size, void* d_ws, size_t ws_size,
                              hipStream_t stream)
{
  const float* x      = (const float*)d_in[0];
  const int*   ei     = (const int*)d_in[1];
  const int*   et     = (const int*)d_in[2];
  const int*   batch  = (const int*)d_in[3];
  const float* Wrel1  = (const float*)d_in[4];
  const float* Wroot1 = (const float*)d_in[5];
  const float* b1     = (const float*)d_in[6];
  const float* Wrel2  = (const float*)d_in[7];
  const float* Wroot2 = (const float*)d_in[8];
  const float* b2     = (const float*)d_in[9];
  const float* Wlin   = (const float*)d_in[10];
  const float* blin   = (const float*)d_in[11];
  float* out = (float*)d_out;
  (void)n_in; (void)ws_size;

  int N = in_sizes[0] / 96;
  int E = in_sizes[1] / 2;
  int G = out_size / 16;
  int NB = 3 * N;
  int nb1 = (NB + 1023) / 1024;
  int SCAN = nb1 * 1024;

  char* w = (char*)d_ws;
  size_t o = 0;
  auto carve = [&](size_t bytes) -> char* {
    char* p = w + o;
    o = (o + bytes + 255) & ~(size_t)255;
    return p;
  };
  float*          Y       = (float*)carve((size_t)N * 384 * 4);          // 76.8 MB
  unsigned short* Xh      = (unsigned short*)carve((size_t)N * 96 * 2);  // 9.6 MB
  unsigned short* Xl      = (unsigned short*)carve((size_t)N * 96 * 2);  // 9.6 MB
  unsigned short* PBh     = (unsigned short*)carve((size_t)2 * 36864 * 2);
  unsigned short* PBl     = (unsigned short*)carve((size_t)2 * 36864 * 2);
  int*            offs    = (int*)carve((size_t)SCAN * 4);
  int*            blockSums = (int*)carve(256 * 4);
  int*            blockOffs = (int*)carve(256 * 4);
  int*            cursor  = (int*)carve((size_t)SCAN * 4);
  int*            payload = (int*)carve((size_t)E * 4);

  hipMemsetAsync(offs, 0, (size_t)SCAN * 4, stream);
  hipMemsetAsync(cursor, 0, (size_t)SCAN * 4, stream);

  k_packW<<<2, THREADS, 0, stream>>>(Wrel1, Wroot1, Wrel2, Wroot2, PBh, PBl);
  k_convX<<<(N * 24 + THREADS - 1) / THREADS, THREADS, 0, stream>>>(
      (const float4*)x, Xh, Xl, N * 24);

  k_hist<<<(E + THREADS - 1) / THREADS, THREADS, 0, stream>>>(ei, et, offs, E, N);
  k_scan1<<<nb1, THREADS, 0, stream>>>(offs, blockSums);
  k_scan2<<<1, THREADS, 0, stream>>>(blockSums, blockOffs, nb1);
  k_scan3<<<nb1, THREADS, 0, stream>>>(offs, blockOffs);
  k_scatter<<<(E + THREADS - 1) / THREADS, THREADS, 0, stream>>>(ei, et, offs, cursor, payload, E, N);

  int gg = (N + 63) / 64;
  int ag = (N + 7) / 8;

  // layer 1
  k_gemm<<<gg, THREADS, 0, stream>>>(Xh, Xl, PBh, PBl, Y, N);
  k_agg3<<<ag, THREADS, 0, stream>>>(Y, offs, payload, b1, Xh, Xl, nullptr, N);
  // layer 2 (reads bf16 X2 written by agg3; writes Y; agg3 finalizes in place)
  k_gemm<<<gg, THREADS, 0, stream>>>(Xh, Xl, PBh + 36864, PBl + 36864, Y, N);
  k_agg3<<<ag, THREADS, 0, stream>>>(Y, offs, payload, b2, nullptr, nullptr, Y, N);

  k_poolfinal<<<G, THREADS, 0, stream>>>(Y, batch, Wlin, blin, out, N, G);
}

// Round 4
// 339.774 us; speedup vs baseline: 5.9635x; 1.2097x over previous
//
#include <hip/hip_runtime.h>

// RGCN 2-layer + mean-pool + linear, MI355X (gfx950).
// r4: aggregate gathers bf16 rel-features (192B/edge vs 384B fp32) written
// directly by the GEMM epilogue; 16-lane-per-node dense gather; scatter
// de-atomicized via rank from hist. GEMM stays split-bf16 (hi/lo) MFMA.

#define THREADS 256

typedef __attribute__((ext_vector_type(8))) short short8v;   // 8 x bf16
typedef __attribute__((ext_vector_type(4))) float f32x4;

__device__ __forceinline__ unsigned short f2bf(float f) {
  union { float f; unsigned u; } v; v.f = f;
  unsigned r = v.u + 0x7FFF + ((v.u >> 16) & 1);   // RNE
  return (unsigned short)(r >> 16);
}
__device__ __forceinline__ float bf2f(unsigned short b) {
  union { unsigned u; float f; } v; v.u = ((unsigned)b) << 16;
  return v.f;
}
__device__ __forceinline__ float bits2f(unsigned u) {
  union { unsigned u; float f; } v; v.u = u;
  return v.f;
}

// ---------- pack W (both layers) into MFMA B-fragment order, split hi/lo ----------
// idx = ((ks*24 + CT)*64 + lane)*8 + j  ->  B[k = ks*32+(lane>>4)*8+j][col = CT*16+(lane&15)]
__global__ __launch_bounds__(256) void k_packW(
    const float* __restrict__ Wrel1, const float* __restrict__ Wroot1,
    const float* __restrict__ Wrel2, const float* __restrict__ Wroot2,
    unsigned short* __restrict__ PBh, unsigned short* __restrict__ PBl)
{
  int lay = blockIdx.x;
  const float* Wroot = lay ? Wroot2 : Wroot1;
  const float* Wrel  = lay ? Wrel2  : Wrel1;
  for (int idx = threadIdx.x; idx < 36864; idx += THREADS) {
    int j    = idx & 7;
    int lane = (idx >> 3) & 63;
    int CT   = (idx >> 9) % 24;
    int ks   = (idx >> 9) / 24;
    int k    = ks * 32 + (lane >> 4) * 8 + j;
    int col  = CT * 16 + (lane & 15);
    int m    = col / 96, jj = col % 96;
    float f  = (m == 0) ? Wroot[k * 96 + jj]
                        : Wrel[((size_t)(m - 1) * 96 + k) * 96 + jj];
    unsigned short h = f2bf(f);
    PBh[(size_t)lay * 36864 + idx] = h;
    PBl[(size_t)lay * 36864 + idx] = f2bf(f - bf2f(h));
  }
}

// ---------- fp32 features -> split bf16 (hi/lo) ----------
__global__ __launch_bounds__(256) void k_convX(
    const float4* __restrict__ X4, unsigned short* __restrict__ Xh,
    unsigned short* __restrict__ Xl, int n4)
{
  int i = blockIdx.x * THREADS + threadIdx.x;
  if (i >= n4) return;
  float4 v = X4[i];
  ushort4 h, l;
  h.x = f2bf(v.x); l.x = f2bf(v.x - bf2f(h.x));
  h.y = f2bf(v.y); l.y = f2bf(v.y - bf2f(h.y));
  h.z = f2bf(v.z); l.z = f2bf(v.z - bf2f(h.z));
  h.w = f2bf(v.w); l.w = f2bf(v.w - bf2f(h.w));
  *(ushort4*)(Xh + (size_t)i * 4) = h;
  *(ushort4*)(Xl + (size_t)i * 4) = l;
}

// ---------- histogram + per-edge rank (removes scatter atomic) ----------
__global__ __launch_bounds__(256) void k_hist(
    const int* __restrict__ ei, const int* __restrict__ et,
    int* __restrict__ cnt, int* __restrict__ rank, int E, int N)
{
  int e = blockIdx.x * THREADS + threadIdx.x;
  if (e >= E) return;
  rank[e] = atomicAdd(&cnt[et[e] * N + ei[E + e]], 1);
}

__global__ __launch_bounds__(256) void k_scan1(int* __restrict__ data, int* __restrict__ blockSums)
{
  __shared__ int sh[256];
  int tid = threadIdx.x;
  size_t base = (size_t)blockIdx.x * 1024 + (size_t)tid * 4;
  int4 v = *(const int4*)(data + base);
  int i0 = v.x, i1 = i0 + v.y, i2 = i1 + v.z, i3 = i2 + v.w;
  int tsum = i3;
  sh[tid] = tsum;
  __syncthreads();
  for (int off = 1; off < 256; off <<= 1) {
    int t = (tid >= off) ? sh[tid - off] : 0;
    __syncthreads();
    sh[tid] += t;
    __syncthreads();
  }
  int excl = sh[tid] - tsum;
  int4 o; o.x = i0 + excl; o.y = i1 + excl; o.z = i2 + excl; o.w = i3 + excl;
  *(int4*)(data + base) = o;
  if (tid == 255) blockSums[blockIdx.x] = sh[255];
}

__global__ __launch_bounds__(256) void k_scan2(const int* __restrict__ blockSums,
                                               int* __restrict__ blockOffs, int nb)
{
  __shared__ int sh[256];
  int tid = threadIdx.x;
  int v = (tid < nb) ? blockSums[tid] : 0;
  sh[tid] = v;
  __syncthreads();
  for (int off = 1; off < 256; off <<= 1) {
    int t = (tid >= off) ? sh[tid - off] : 0;
    __syncthreads();
    sh[tid] += t;
    __syncthreads();
  }
  blockOffs[tid] = sh[tid] - v;
}

__global__ __launch_bounds__(256) void k_scan3(int* __restrict__ data, const int* __restrict__ blockOffs)
{
  int tid = threadIdx.x;
  size_t base = (size_t)blockIdx.x * 1024 + (size_t)tid * 4;
  int add = blockOffs[blockIdx.x];
  int4 v = *(const int4*)(data + base);
  v.x += add; v.y += add; v.z += add; v.w += add;
  *(int4*)(data + base) = v;
}

__global__ __launch_bounds__(256) void k_scatter(
    const int* __restrict__ ei, const int* __restrict__ et,
    const int* __restrict__ offs, const int* __restrict__ rank,
    int* __restrict__ payload, int E, int N)
{
  int e = blockIdx.x * THREADS + threadIdx.x;
  if (e >= E) return;
  int bucket = et[e] * N + ei[E + e];
  int base = (bucket == 0) ? 0 : offs[bucket - 1];
  payload[base + rank[e]] = ei[e];
}

// ---------- MFMA GEMM: [Yroot fp32 | Hrel bf16] = X @ [Wroot|Wrel0..2], split-bf16 ----------
// Block = 64 rows x 384 cols; wave wv owns cols [wv*96, wv*96+96).
__global__ __launch_bounds__(256) void k_gemm(
    const unsigned short* __restrict__ Xh, const unsigned short* __restrict__ Xl,
    const unsigned short* __restrict__ PBh, const unsigned short* __restrict__ PBl,
    float* __restrict__ Yroot, unsigned short* __restrict__ Hrel, int nRows)
{
  int wv = threadIdx.x >> 6, lane = threadIdx.x & 63;
  int lr = lane & 15, lq = lane >> 4;
  int r0 = blockIdx.x * 64;

  f32x4 acc[4][6];
#pragma unroll
  for (int rt = 0; rt < 4; ++rt)
#pragma unroll
    for (int ct = 0; ct < 6; ++ct) acc[rt][ct] = (f32x4){0.f, 0.f, 0.f, 0.f};

#pragma unroll 1
  for (int ks = 0; ks < 3; ++ks) {
    short8v Ah[4], Al[4];
#pragma unroll
    for (int rt = 0; rt < 4; ++rt) {
      int row = r0 + rt * 16 + lr;
      if (row >= nRows) row = nRows - 1;          // clamp; stores guarded
      size_t off = (size_t)row * 96 + ks * 32 + lq * 8;
      Ah[rt] = *(const short8v*)(Xh + off);
      Al[rt] = *(const short8v*)(Xl + off);
    }
#pragma unroll
    for (int ct = 0; ct < 6; ++ct) {
      int CT = wv * 6 + ct;
      size_t boff = ((size_t)(ks * 24 + CT) * 64 + lane) * 8;
      short8v Bh = *(const short8v*)(PBh + boff);
      short8v Bl = *(const short8v*)(PBl + boff);
#pragma unroll
      for (int rt = 0; rt < 4; ++rt) {
        acc[rt][ct] = __builtin_amdgcn_mfma_f32_16x16x32_bf16(Ah[rt], Bh, acc[rt][ct], 0, 0, 0);
        acc[rt][ct] = __builtin_amdgcn_mfma_f32_16x16x32_bf16(Al[rt], Bh, acc[rt][ct], 0, 0, 0);
        acc[rt][ct] = __builtin_amdgcn_mfma_f32_16x16x32_bf16(Ah[rt], Bl, acc[rt][ct], 0, 0, 0);
      }
    }
  }

  if (wv == 0) {  // root part, fp32
#pragma unroll
    for (int rt = 0; rt < 4; ++rt)
#pragma unroll
      for (int q = 0; q < 4; ++q) {
        int row = r0 + rt * 16 + lq * 4 + q;
        if (row < nRows) {
          float* yp = Yroot + (size_t)row * 96 + lr;
#pragma unroll
          for (int ct = 0; ct < 6; ++ct) yp[ct * 16] = acc[rt][ct][q];
        }
      }
  } else {        // relation part, bf16
    int r = wv - 1;
#pragma unroll
    for (int rt = 0; rt < 4; ++rt)
#pragma unroll
      for (int q = 0; q < 4; ++q) {
        int row = r0 + rt * 16 + lq * 4 + q;
        if (row < nRows) {
          unsigned short* hp = Hrel + ((size_t)r * nRows + row) * 96 + lr;
#pragma unroll
          for (int ct = 0; ct < 6; ++ct) hp[ct * 16] = f2bf(acc[rt][ct][q]);
        }
      }
  }
}

// ---------- aggregate: v = root + bias + sum_r mean_r(bf16 gather); relu ----------
// 16 lanes per node; lane owns channels 6l..6l+5 (12B dense per gather).
// Writes split-bf16 (next GEMM input) or plain bf16 (final h for pooling).
__global__ __launch_bounds__(256) void k_agg3(
    const float* __restrict__ Yroot, const unsigned short* __restrict__ Hrel,
    const int* __restrict__ offs, const int* __restrict__ payload,
    const float* __restrict__ bias,
    unsigned int* outH, unsigned int* outL, unsigned int* outF, int N)
{
  int node = blockIdx.x * 16 + (threadIdx.x >> 4);
  int l = threadIdx.x & 15;
  if (node >= N) return;

  const float2* yp = (const float2*)(Yroot + (size_t)node * 96) + 3 * l;
  const float2* bp = (const float2*)bias + 3 * l;
  float2 y0 = yp[0], y1 = yp[1], y2 = yp[2];
  float2 b0 = bp[0], b1 = bp[1], b2 = bp[2];
  float v[6];
  v[0] = y0.x + b0.x; v[1] = y0.y + b0.y;
  v[2] = y1.x + b1.x; v[3] = y1.y + b1.y;
  v[4] = y2.x + b2.x; v[5] = y2.y + b2.y;

#pragma unroll
  for (int r = 0; r < 3; ++r) {
    int bkt = r * N + node;
    int s = (bkt == 0) ? 0 : offs[bkt - 1];
    int e = offs[bkt];
    const unsigned int* base = (const unsigned int*)(Hrel + (size_t)r * N * 96);
    float a[6] = {0.f, 0.f, 0.f, 0.f, 0.f, 0.f};
    int t = s;
    for (; t + 1 < e; t += 2) {                    // 2x unroll for MLP
      const unsigned int* h0 = base + (size_t)payload[t] * 48 + 3 * l;
      const unsigned int* h1 = base + (size_t)payload[t + 1] * 48 + 3 * l;
      unsigned u0 = h0[0], u1 = h0[1], u2 = h0[2];
      unsigned w0 = h1[0], w1 = h1[1], w2 = h1[2];
      a[0] += bits2f(u0 << 16); a[1] += bits2f(u0 & 0xFFFF0000u);
      a[2] += bits2f(u1 << 16); a[3] += bits2f(u1 & 0xFFFF0000u);
      a[4] += bits2f(u2 << 16); a[5] += bits2f(u2 & 0xFFFF0000u);
      a[0] += bits2f(w0 << 16); a[1] += bits2f(w0 & 0xFFFF0000u);
      a[2] += bits2f(w1 << 16); a[3] += bits2f(w1 & 0xFFFF0000u);
      a[4] += bits2f(w2 << 16); a[5] += bits2f(w2 & 0xFFFF0000u);
    }
    if (t < e) {
      const unsigned int* h0 = base + (size_t)payload[t] * 48 + 3 * l;
      unsigned u0 = h0[0], u1 = h0[1], u2 = h0[2];
      a[0] += bits2f(u0 << 16); a[1] += bits2f(u0 & 0xFFFF0000u);
      a[2] += bits2f(u1 << 16); a[3] += bits2f(u1 & 0xFFFF0000u);
      a[4] += bits2f(u2 << 16); a[5] += bits2f(u2 & 0xFFFF0000u);
    }
    float inv = (e > s) ? 1.0f / (float)(e - s) : 0.0f;
#pragma unroll
    for (int i = 0; i < 6; ++i) v[i] += a[i] * inv;
  }
#pragma unroll
  for (int i = 0; i < 6; ++i) v[i] = fmaxf(v[i], 0.f);

  size_t ob = (size_t)node * 48 + 3 * l;
  if (outF) {
    outF[ob]     = ((unsigned)f2bf(v[1]) << 16) | f2bf(v[0]);
    outF[ob + 1] = ((unsigned)f2bf(v[3]) << 16) | f2bf(v[2]);
    outF[ob + 2] = ((unsigned)f2bf(v[5]) << 16) | f2bf(v[4]);
  } else {
    unsigned short h[6], lo[6];
#pragma unroll
    for (int i = 0; i < 6; ++i) { h[i] = f2bf(v[i]); lo[i] = f2bf(v[i] - bf2f(h[i])); }
    outH[ob]     = ((unsigned)h[1] << 16) | h[0];
    outH[ob + 1] = ((unsigned)h[3] << 16) | h[2];
    outH[ob + 2] = ((unsigned)h[5] << 16) | h[4];
    outL[ob]     = ((unsigned)lo[1] << 16) | lo[0];
    outL[ob + 1] = ((unsigned)lo[3] << 16) | lo[2];
    outL[ob + 2] = ((unsigned)lo[5] << 16) | lo[4];
  }
}

// ---------- one block per graph: mean pool (bf16 rows) + 96->16 linear ----------
__global__ __launch_bounds__(256) void k_poolfinal(
    const unsigned int* __restrict__ H, const int* __restrict__ batch,
    const float* __restrict__ Wlin, const float* __restrict__ blin,
    float* __restrict__ out, int N, int G)
{
  int g = blockIdx.x;
  int tid = threadIdx.x;
  int lo = 0, hi = N;
  while (lo < hi) { int m = (lo + hi) >> 1; if (batch[m] < g) lo = m + 1; else hi = m; }
  int s = lo; hi = N;
  while (lo < hi) { int m = (lo + hi) >> 1; if (batch[m] < g + 1) lo = m + 1; else hi = m; }
  int e = lo;

  int grp = tid >> 4, l = tid & 15;
  float a[6] = {0.f, 0.f, 0.f, 0.f, 0.f, 0.f};
  for (int i = s + grp; i < e; i += 16) {
    const unsigned int* hp = H + (size_t)i * 48 + 3 * l;
    unsigned u0 = hp[0], u1 = hp[1], u2 = hp[2];
    a[0] += bits2f(u0 << 16); a[1] += bits2f(u0 & 0xFFFF0000u);
    a[2] += bits2f(u1 << 16); a[3] += bits2f(u1 & 0xFFFF0000u);
    a[4] += bits2f(u2 << 16); a[5] += bits2f(u2 & 0xFFFF0000u);
  }
  __shared__ float sh[16][96];
  __shared__ float pooled[96];
#pragma unroll
  for (int i = 0; i < 6; ++i) sh[grp][6 * l + i] = a[i];
  __syncthreads();
  if (tid < 96) {
    float t = 0.f;
#pragma unroll
    for (int j = 0; j < 16; ++j) t += sh[j][tid];
    float inv = (e > s) ? 1.0f / (float)(e - s) : 0.0f;
    pooled[tid] = t * inv;
  }
  __syncthreads();
  if (tid < 16) {
    float acc = blin[tid];
    for (int k = 0; k < 96; ++k) acc = fmaf(pooled[k], Wlin[k * 16 + tid], acc);
    out[(size_t)g * 16 + tid] = acc;
  }
}

extern "C" void kernel_launch(void* const* d_in, const int* in_sizes, int n_in,
                              void* d_out, int out_size, void* d_ws, size_t ws_size,
                              hipStream_t stream)
{
  const float* x      = (const float*)d_in[0];
  const int*   ei     = (const int*)d_in[1];
  const int*   et     = (const int*)d_in[2];
  const int*   batch  = (const int*)d_in[3];
  const float* Wrel1  = (const float*)d_in[4];
  const float* Wroot1 = (const float*)d_in[5];
  const float* b1     = (const float*)d_in[6];
  const float* Wrel2  = (const float*)d_in[7];
  const float* Wroot2 = (const float*)d_in[8];
  const float* b2     = (const float*)d_in[9];
  const float* Wlin   = (const float*)d_in[10];
  const float* blin   = (const float*)d_in[11];
  float* out = (float*)d_out;
  (void)n_in; (void)ws_size;

  int N = in_sizes[0] / 96;
  int E = in_sizes[1] / 2;
  int G = out_size / 16;
  int NB = 3 * N;
  int nb1 = (NB + 1023) / 1024;
  int SCAN = nb1 * 1024;

  char* w = (char*)d_ws;
  size_t o = 0;
  auto carve = [&](size_t bytes) -> char* {
    char* p = w + o;
    o = (o + bytes + 255) & ~(size_t)255;
    return p;
  };
  float*          Yroot = (float*)carve((size_t)N * 96 * 4);                 // 19.2 MB
  unsigned short* Hrel  = (unsigned short*)carve((size_t)3 * N * 96 * 2);    // 28.8 MB
  unsigned short* Xh    = (unsigned short*)carve((size_t)N * 96 * 2);        // 9.6 MB
  unsigned short* Xl    = (unsigned short*)carve((size_t)N * 96 * 2);        // 9.6 MB
  unsigned short* Hout  = (unsigned short*)carve((size_t)N * 96 * 2);        // 9.6 MB
  unsigned short* PBh   = (unsigned short*)carve((size_t)2 * 36864 * 2);
  unsigned short* PBl   = (unsigned short*)carve((size_t)2 * 36864 * 2);
  int*            offs  = (int*)carve((size_t)SCAN * 4);
  int*            blockSums = (int*)carve(256 * 4);
  int*            blockOffs = (int*)carve(256 * 4);
  int*            rank  = (int*)carve((size_t)E * 4);
  int*            payload = (int*)carve((size_t)E * 4);

  hipMemsetAsync(offs, 0, (size_t)SCAN * 4, stream);

  k_packW<<<2, THREADS, 0, stream>>>(Wrel1, Wroot1, Wrel2, Wroot2, PBh, PBl);
  k_convX<<<(N * 24 + THREADS - 1) / THREADS, THREADS, 0, stream>>>(
      (const float4*)x, Xh, Xl, N * 24);

  k_hist<<<(E + THREADS - 1) / THREADS, THREADS, 0, stream>>>(ei, et, offs, rank, E, N);
  k_scan1<<<nb1, THREADS, 0, stream>>>(offs, blockSums);
  k_scan2<<<1, THREADS, 0, stream>>>(blockSums, blockOffs, nb1);
  k_scan3<<<nb1, THREADS, 0, stream>>>(offs, blockOffs);
  k_scatter<<<(E + THREADS - 1) / THREADS, THREADS, 0, stream>>>(ei, et, offs, rank, payload, E, N);

  int gg = (N + 63) / 64;
  int ag = (N + 15) / 16;

  // layer 1
  k_gemm<<<gg, THREADS, 0, stream>>>(Xh, Xl, PBh, PBl, Yroot, Hrel, N);
  k_agg3<<<ag, THREADS, 0, stream>>>(Yroot, Hrel, offs, payload, b1,
                                     (unsigned int*)Xh, (unsigned int*)Xl, nullptr, N);
  // layer 2
  k_gemm<<<gg, THREADS, 0, stream>>>(Xh, Xl, PBh + 36864, PBl + 36864, Yroot, Hrel, N);
  k_agg3<<<ag, THREADS, 0, stream>>>(Yroot, Hrel, offs, payload, b2,
                                     nullptr, nullptr, (unsigned int*)Hout, N);

  k_poolfinal<<<G, THREADS, 0, stream>>>((const unsigned int*)Hout, batch, Wlin, blin, out, N, G);
}

// Round 5
// 303.132 us; speedup vs baseline: 6.6843x; 1.1209x over previous
//
#include <hip/hip_runtime.h>

// RGCN 2-layer + mean-pool + linear, MI355X (gfx950).
// r5: k_packW parallelized (one elem/thread; was 2x256 threads = 45-62us
// latency chain). agg3 gather loop unrolled 4x for MLP. hist caches bucket[].
// GEMM: split-bf16 (hi/lo) MFMA, B pre-packed in fragment order, no LDS.

#define THREADS 256

typedef __attribute__((ext_vector_type(8))) short short8v;   // 8 x bf16
typedef __attribute__((ext_vector_type(4))) float f32x4;

__device__ __forceinline__ unsigned short f2bf(float f) {
  union { float f; unsigned u; } v; v.f = f;
  unsigned r = v.u + 0x7FFF + ((v.u >> 16) & 1);   // RNE
  return (unsigned short)(r >> 16);
}
__device__ __forceinline__ float bf2f(unsigned short b) {
  union { unsigned u; float f; } v; v.u = ((unsigned)b) << 16;
  return v.f;
}
__device__ __forceinline__ float bits2f(unsigned u) {
  union { unsigned u; float f; } v; v.u = u;
  return v.f;
}

// ---------- pack W into MFMA B-fragment order, split hi/lo; 1 elem/thread ----------
// idx = ((ks*24 + CT)*64 + lane)*8 + j  ->  B[k = ks*32+(lane>>4)*8+j][col = CT*16+(lane&15)]
__global__ __launch_bounds__(256) void k_packW(
    const float* __restrict__ Wrel1, const float* __restrict__ Wroot1,
    const float* __restrict__ Wrel2, const float* __restrict__ Wroot2,
    unsigned short* __restrict__ PBh, unsigned short* __restrict__ PBl)
{
  int lay = blockIdx.x / 144;
  int idx = (blockIdx.x % 144) * 256 + threadIdx.x;
  const float* Wroot = lay ? Wroot2 : Wroot1;
  const float* Wrel  = lay ? Wrel2  : Wrel1;
  int j    = idx & 7;
  int lane = (idx >> 3) & 63;
  int CT   = (idx >> 9) % 24;
  int ks   = (idx >> 9) / 24;
  int k    = ks * 32 + (lane >> 4) * 8 + j;
  int col  = CT * 16 + (lane & 15);
  int m    = col / 96, jj = col % 96;
  float f  = (m == 0) ? Wroot[k * 96 + jj]
                      : Wrel[((size_t)(m - 1) * 96 + k) * 96 + jj];
  unsigned short h = f2bf(f);
  PBh[(size_t)lay * 36864 + idx] = h;
  PBl[(size_t)lay * 36864 + idx] = f2bf(f - bf2f(h));
}

// ---------- fp32 features -> split bf16 (hi/lo) ----------
__global__ __launch_bounds__(256) void k_convX(
    const float4* __restrict__ X4, unsigned short* __restrict__ Xh,
    unsigned short* __restrict__ Xl, int n4)
{
  int i = blockIdx.x * THREADS + threadIdx.x;
  if (i >= n4) return;
  float4 v = X4[i];
  ushort4 h, l;
  h.x = f2bf(v.x); l.x = f2bf(v.x - bf2f(h.x));
  h.y = f2bf(v.y); l.y = f2bf(v.y - bf2f(h.y));
  h.z = f2bf(v.z); l.z = f2bf(v.z - bf2f(h.z));
  h.w = f2bf(v.w); l.w = f2bf(v.w - bf2f(h.w));
  *(ushort4*)(Xh + (size_t)i * 4) = h;
  *(ushort4*)(Xl + (size_t)i * 4) = l;
}

// ---------- histogram + per-edge rank + bucket cache ----------
__global__ __launch_bounds__(256) void k_hist(
    const int* __restrict__ ei, const int* __restrict__ et,
    int* __restrict__ cnt, int* __restrict__ rank, int* __restrict__ bucket,
    int E, int N)
{
  int e = blockIdx.x * THREADS + threadIdx.x;
  if (e >= E) return;
  int b = et[e] * N + ei[E + e];
  bucket[e] = b;
  rank[e] = atomicAdd(&cnt[b], 1);
}

__global__ __launch_bounds__(256) void k_scan1(int* __restrict__ data, int* __restrict__ blockSums)
{
  __shared__ int sh[256];
  int tid = threadIdx.x;
  size_t base = (size_t)blockIdx.x * 1024 + (size_t)tid * 4;
  int4 v = *(const int4*)(data + base);
  int i0 = v.x, i1 = i0 + v.y, i2 = i1 + v.z, i3 = i2 + v.w;
  int tsum = i3;
  sh[tid] = tsum;
  __syncthreads();
  for (int off = 1; off < 256; off <<= 1) {
    int t = (tid >= off) ? sh[tid - off] : 0;
    __syncthreads();
    sh[tid] += t;
    __syncthreads();
  }
  int excl = sh[tid] - tsum;
  int4 o; o.x = i0 + excl; o.y = i1 + excl; o.z = i2 + excl; o.w = i3 + excl;
  *(int4*)(data + base) = o;
  if (tid == 255) blockSums[blockIdx.x] = sh[255];
}

__global__ __launch_bounds__(256) void k_scan2(const int* __restrict__ blockSums,
                                               int* __restrict__ blockOffs, int nb)
{
  __shared__ int sh[256];
  int tid = threadIdx.x;
  int v = (tid < nb) ? blockSums[tid] : 0;
  sh[tid] = v;
  __syncthreads();
  for (int off = 1; off < 256; off <<= 1) {
    int t = (tid >= off) ? sh[tid - off] : 0;
    __syncthreads();
    sh[tid] += t;
    __syncthreads();
  }
  blockOffs[tid] = sh[tid] - v;
}

__global__ __launch_bounds__(256) void k_scan3(int* __restrict__ data, const int* __restrict__ blockOffs)
{
  int tid = threadIdx.x;
  size_t base = (size_t)blockIdx.x * 1024 + (size_t)tid * 4;
  int add = blockOffs[blockIdx.x];
  int4 v = *(const int4*)(data + base);
  v.x += add; v.y += add; v.z += add; v.w += add;
  *(int4*)(data + base) = v;
}

__global__ __launch_bounds__(256) void k_scatter(
    const int* __restrict__ ei, const int* __restrict__ offs,
    const int* __restrict__ rank, const int* __restrict__ bucket,
    int* __restrict__ payload, int E)
{
  int e = blockIdx.x * THREADS + threadIdx.x;
  if (e >= E) return;
  int b = bucket[e];
  int base = (b == 0) ? 0 : offs[b - 1];
  payload[base + rank[e]] = ei[e];
}

// ---------- MFMA GEMM: [Yroot fp32 | Hrel bf16] = X @ [Wroot|Wrel0..2], split-bf16 ----------
// Block = 64 rows x 384 cols; wave wv owns cols [wv*96, wv*96+96).
__global__ __launch_bounds__(256) void k_gemm(
    const unsigned short* __restrict__ Xh, const unsigned short* __restrict__ Xl,
    const unsigned short* __restrict__ PBh, const unsigned short* __restrict__ PBl,
    float* __restrict__ Yroot, unsigned short* __restrict__ Hrel, int nRows)
{
  int wv = threadIdx.x >> 6, lane = threadIdx.x & 63;
  int lr = lane & 15, lq = lane >> 4;
  int r0 = blockIdx.x * 64;

  f32x4 acc[4][6];
#pragma unroll
  for (int rt = 0; rt < 4; ++rt)
#pragma unroll
    for (int ct = 0; ct < 6; ++ct) acc[rt][ct] = (f32x4){0.f, 0.f, 0.f, 0.f};

#pragma unroll 1
  for (int ks = 0; ks < 3; ++ks) {
    short8v Ah[4], Al[4];
#pragma unroll
    for (int rt = 0; rt < 4; ++rt) {
      int row = r0 + rt * 16 + lr;
      if (row >= nRows) row = nRows - 1;          // clamp; stores guarded
      size_t off = (size_t)row * 96 + ks * 32 + lq * 8;
      Ah[rt] = *(const short8v*)(Xh + off);
      Al[rt] = *(const short8v*)(Xl + off);
    }
#pragma unroll
    for (int ct = 0; ct < 6; ++ct) {
      int CT = wv * 6 + ct;
      size_t boff = ((size_t)(ks * 24 + CT) * 64 + lane) * 8;
      short8v Bh = *(const short8v*)(PBh + boff);
      short8v Bl = *(const short8v*)(PBl + boff);
#pragma unroll
      for (int rt = 0; rt < 4; ++rt) {
        acc[rt][ct] = __builtin_amdgcn_mfma_f32_16x16x32_bf16(Ah[rt], Bh, acc[rt][ct], 0, 0, 0);
        acc[rt][ct] = __builtin_amdgcn_mfma_f32_16x16x32_bf16(Al[rt], Bh, acc[rt][ct], 0, 0, 0);
        acc[rt][ct] = __builtin_amdgcn_mfma_f32_16x16x32_bf16(Ah[rt], Bl, acc[rt][ct], 0, 0, 0);
      }
    }
  }

  if (wv == 0) {  // root part, fp32
#pragma unroll
    for (int rt = 0; rt < 4; ++rt)
#pragma unroll
      for (int q = 0; q < 4; ++q) {
        int row = r0 + rt * 16 + lq * 4 + q;
        if (row < nRows) {
          float* yp = Yroot + (size_t)row * 96 + lr;
#pragma unroll
          for (int ct = 0; ct < 6; ++ct) yp[ct * 16] = acc[rt][ct][q];
        }
      }
  } else {        // relation part, bf16
    int r = wv - 1;
#pragma unroll
    for (int rt = 0; rt < 4; ++rt)
#pragma unroll
      for (int q = 0; q < 4; ++q) {
        int row = r0 + rt * 16 + lq * 4 + q;
        if (row < nRows) {
          unsigned short* hp = Hrel + ((size_t)r * nRows + row) * 96 + lr;
#pragma unroll
          for (int ct = 0; ct < 6; ++ct) hp[ct * 16] = f2bf(acc[rt][ct][q]);
        }
      }
  }
}

// ---------- aggregate: v = root + bias + sum_r mean_r(bf16 gather); relu ----------
// 16 lanes/node, lane owns channels 6l..6l+5 (12B dense per gather);
// edge loop unrolled 4x (4 independent gather chains for MLP).
__global__ __launch_bounds__(256) void k_agg3(
    const float* __restrict__ Yroot, const unsigned short* __restrict__ Hrel,
    const int* __restrict__ offs, const int* __restrict__ payload,
    const float* __restrict__ bias,
    unsigned int* outH, unsigned int* outL, unsigned int* outF, int N)
{
  int node = blockIdx.x * 16 + (threadIdx.x >> 4);
  int l = threadIdx.x & 15;
  if (node >= N) return;

  const float2* yp = (const float2*)(Yroot + (size_t)node * 96) + 3 * l;
  const float2* bp = (const float2*)bias + 3 * l;
  float2 y0 = yp[0], y1 = yp[1], y2 = yp[2];
  float2 b0 = bp[0], b1 = bp[1], b2 = bp[2];
  float v[6];
  v[0] = y0.x + b0.x; v[1] = y0.y + b0.y;
  v[2] = y1.x + b1.x; v[3] = y1.y + b1.y;
  v[4] = y2.x + b2.x; v[5] = y2.y + b2.y;

#pragma unroll
  for (int r = 0; r < 3; ++r) {
    int bkt = r * N + node;
    int s = (bkt == 0) ? 0 : offs[bkt - 1];
    int e = offs[bkt];
    const unsigned int* base = (const unsigned int*)(Hrel + (size_t)r * N * 96);
    float a[6] = {0.f, 0.f, 0.f, 0.f, 0.f, 0.f};
    int t = s;
    for (; t + 3 < e; t += 4) {
      int p0 = payload[t], p1 = payload[t + 1], p2 = payload[t + 2], p3 = payload[t + 3];
      const unsigned int* h0 = base + (size_t)p0 * 48 + 3 * l;
      const unsigned int* h1 = base + (size_t)p1 * 48 + 3 * l;
      const unsigned int* h2 = base + (size_t)p2 * 48 + 3 * l;
      const unsigned int* h3 = base + (size_t)p3 * 48 + 3 * l;
      unsigned u0 = h0[0], u1 = h0[1], u2 = h0[2];
      unsigned w0 = h1[0], w1 = h1[1], w2 = h1[2];
      unsigned x0 = h2[0], x1 = h2[1], x2 = h2[2];
      unsigned z0 = h3[0], z1 = h3[1], z2 = h3[2];
      a[0] += bits2f(u0 << 16); a[1] += bits2f(u0 & 0xFFFF0000u);
      a[2] += bits2f(u1 << 16); a[3] += bits2f(u1 & 0xFFFF0000u);
      a[4] += bits2f(u2 << 16); a[5] += bits2f(u2 & 0xFFFF0000u);
      a[0] += bits2f(w0 << 16); a[1] += bits2f(w0 & 0xFFFF0000u);
      a[2] += bits2f(w1 << 16); a[3] += bits2f(w1 & 0xFFFF0000u);
      a[4] += bits2f(w2 << 16); a[5] += bits2f(w2 & 0xFFFF0000u);
      a[0] += bits2f(x0 << 16); a[1] += bits2f(x0 & 0xFFFF0000u);
      a[2] += bits2f(x1 << 16); a[3] += bits2f(x1 & 0xFFFF0000u);
      a[4] += bits2f(x2 << 16); a[5] += bits2f(x2 & 0xFFFF0000u);
      a[0] += bits2f(z0 << 16); a[1] += bits2f(z0 & 0xFFFF0000u);
      a[2] += bits2f(z1 << 16); a[3] += bits2f(z1 & 0xFFFF0000u);
      a[4] += bits2f(z2 << 16); a[5] += bits2f(z2 & 0xFFFF0000u);
    }
    for (; t < e; ++t) {
      const unsigned int* h0 = base + (size_t)payload[t] * 48 + 3 * l;
      unsigned u0 = h0[0], u1 = h0[1], u2 = h0[2];
      a[0] += bits2f(u0 << 16); a[1] += bits2f(u0 & 0xFFFF0000u);
      a[2] += bits2f(u1 << 16); a[3] += bits2f(u1 & 0xFFFF0000u);
      a[4] += bits2f(u2 << 16); a[5] += bits2f(u2 & 0xFFFF0000u);
    }
    float inv = (e > s) ? 1.0f / (float)(e - s) : 0.0f;
#pragma unroll
    for (int i = 0; i < 6; ++i) v[i] += a[i] * inv;
  }
#pragma unroll
  for (int i = 0; i < 6; ++i) v[i] = fmaxf(v[i], 0.f);

  size_t ob = (size_t)node * 48 + 3 * l;
  if (outF) {
    outF[ob]     = ((unsigned)f2bf(v[1]) << 16) | f2bf(v[0]);
    outF[ob + 1] = ((unsigned)f2bf(v[3]) << 16) | f2bf(v[2]);
    outF[ob + 2] = ((unsigned)f2bf(v[5]) << 16) | f2bf(v[4]);
  } else {
    unsigned short h[6], lo[6];
#pragma unroll
    for (int i = 0; i < 6; ++i) { h[i] = f2bf(v[i]); lo[i] = f2bf(v[i] - bf2f(h[i])); }
    outH[ob]     = ((unsigned)h[1] << 16) | h[0];
    outH[ob + 1] = ((unsigned)h[3] << 16) | h[2];
    outH[ob + 2] = ((unsigned)h[5] << 16) | h[4];
    outL[ob]     = ((unsigned)lo[1] << 16) | lo[0];
    outL[ob + 1] = ((unsigned)lo[3] << 16) | lo[2];
    outL[ob + 2] = ((unsigned)lo[5] << 16) | lo[4];
  }
}

// ---------- one block per graph: mean pool (bf16 rows) + 96->16 linear ----------
__global__ __launch_bounds__(256) void k_poolfinal(
    const unsigned int* __restrict__ H, const int* __restrict__ batch,
    const float* __restrict__ Wlin, const float* __restrict__ blin,
    float* __restrict__ out, int N, int G)
{
  int g = blockIdx.x;
  int tid = threadIdx.x;
  int lo = 0, hi = N;
  while (lo < hi) { int m = (lo + hi) >> 1; if (batch[m] < g) lo = m + 1; else hi = m; }
  int s = lo; hi = N;
  while (lo < hi) { int m = (lo + hi) >> 1; if (batch[m] < g + 1) lo = m + 1; else hi = m; }
  int e = lo;

  int grp = tid >> 4, l = tid & 15;
  float a[6] = {0.f, 0.f, 0.f, 0.f, 0.f, 0.f};
  for (int i = s + grp; i < e; i += 16) {
    const unsigned int* hp = H + (size_t)i * 48 + 3 * l;
    unsigned u0 = hp[0], u1 = hp[1], u2 = hp[2];
    a[0] += bits2f(u0 << 16); a[1] += bits2f(u0 & 0xFFFF0000u);
    a[2] += bits2f(u1 << 16); a[3] += bits2f(u1 & 0xFFFF0000u);
    a[4] += bits2f(u2 << 16); a[5] += bits2f(u2 & 0xFFFF0000u);
  }
  __shared__ float sh[16][96];
  __shared__ float pooled[96];
#pragma unroll
  for (int i = 0; i < 6; ++i) sh[grp][6 * l + i] = a[i];
  __syncthreads();
  if (tid < 96) {
    float t = 0.f;
#pragma unroll
    for (int j = 0; j < 16; ++j) t += sh[j][tid];
    float inv = (e > s) ? 1.0f / (float)(e - s) : 0.0f;
    pooled[tid] = t * inv;
  }
  __syncthreads();
  if (tid < 16) {
    float acc = blin[tid];
    for (int k = 0; k < 96; ++k) acc = fmaf(pooled[k], Wlin[k * 16 + tid], acc);
    out[(size_t)g * 16 + tid] = acc;
  }
}

extern "C" void kernel_launch(void* const* d_in, const int* in_sizes, int n_in,
                              void* d_out, int out_size, void* d_ws, size_t ws_size,
                              hipStream_t stream)
{
  const float* x      = (const float*)d_in[0];
  const int*   ei     = (const int*)d_in[1];
  const int*   et     = (const int*)d_in[2];
  const int*   batch  = (const int*)d_in[3];
  const float* Wrel1  = (const float*)d_in[4];
  const float* Wroot1 = (const float*)d_in[5];
  const float* b1     = (const float*)d_in[6];
  const float* Wrel2  = (const float*)d_in[7];
  const float* Wroot2 = (const float*)d_in[8];
  const float* b2     = (const float*)d_in[9];
  const float* Wlin   = (const float*)d_in[10];
  const float* blin   = (const float*)d_in[11];
  float* out = (float*)d_out;
  (void)n_in; (void)ws_size;

  int N = in_sizes[0] / 96;
  int E = in_sizes[1] / 2;
  int G = out_size / 16;
  int NB = 3 * N;
  int nb1 = (NB + 1023) / 1024;
  int SCAN = nb1 * 1024;

  char* w = (char*)d_ws;
  size_t o = 0;
  auto carve = [&](size_t bytes) -> char* {
    char* p = w + o;
    o = (o + bytes + 255) & ~(size_t)255;
    return p;
  };
  float*          Yroot = (float*)carve((size_t)N * 96 * 4);                 // 19.2 MB
  unsigned short* Hrel  = (unsigned short*)carve((size_t)3 * N * 96 * 2);    // 28.8 MB
  unsigned short* Xh    = (unsigned short*)carve((size_t)N * 96 * 2);        // 9.6 MB
  unsigned short* Xl    = (unsigned short*)carve((size_t)N * 96 * 2);        // 9.6 MB
  unsigned short* Hout  = (unsigned short*)carve((size_t)N * 96 * 2);        // 9.6 MB
  unsigned short* PBh   = (unsigned short*)carve((size_t)2 * 36864 * 2);
  unsigned short* PBl   = (unsigned short*)carve((size_t)2 * 36864 * 2);
  int*            offs  = (int*)carve((size_t)SCAN * 4);
  int*            blockSums = (int*)carve(256 * 4);
  int*            blockOffs = (int*)carve(256 * 4);
  int*            rank  = (int*)carve((size_t)E * 4);
  int*            bucket= (int*)carve((size_t)E * 4);
  int*            payload = (int*)carve((size_t)E * 4);

  hipMemsetAsync(offs, 0, (size_t)SCAN * 4, stream);

  k_packW<<<288, THREADS, 0, stream>>>(Wrel1, Wroot1, Wrel2, Wroot2, PBh, PBl);
  k_convX<<<(N * 24 + THREADS - 1) / THREADS, THREADS, 0, stream>>>(
      (const float4*)x, Xh, Xl, N * 24);

  k_hist<<<(E + THREADS - 1) / THREADS, THREADS, 0, stream>>>(ei, et, offs, rank, bucket, E, N);
  k_scan1<<<nb1, THREADS, 0, stream>>>(offs, blockSums);
  k_scan2<<<1, THREADS, 0, stream>>>(blockSums, blockOffs, nb1);
  k_scan3<<<nb1, THREADS, 0, stream>>>(offs, blockOffs);
  k_scatter<<<(E + THREADS - 1) / THREADS, THREADS, 0, stream>>>(ei, offs, rank, bucket, payload, E);

  int gg = (N + 63) / 64;
  int ag = (N + 15) / 16;

  // layer 1
  k_gemm<<<gg, THREADS, 0, stream>>>(Xh, Xl, PBh, PBl, Yroot, Hrel, N);
  k_agg3<<<ag, THREADS, 0, stream>>>(Yroot, Hrel, offs, payload, b1,
                                     (unsigned int*)Xh, (unsigned int*)Xl, nullptr, N);
  // layer 2
  k_gemm<<<gg, THREADS, 0, stream>>>(Xh, Xl, PBh + 36864, PBl + 36864, Yroot, Hrel, N);
  k_agg3<<<ag, THREADS, 0, stream>>>(Yroot, Hrel, offs, payload, b2,
                                     nullptr, nullptr, (unsigned int*)Hout, N);

  k_poolfinal<<<G, THREADS, 0, stream>>>((const unsigned int*)Hout, batch, Wlin, blin, out, N, G);
}

// Round 6
// 292.121 us; speedup vs baseline: 6.9363x; 1.0377x over previous
//
#include <hip/hip_runtime.h>

// RGCN 2-layer + mean-pool + linear, MI355X (gfx950).
// r6: pi-permuted GEMM epilogue (channel perm pi(c)=(c%16)*6+c/16) makes all
// output stores lane-contiguous (24B/12B per lane, full coalesced rows).
// Downstream is position-based; layer-2 B-pack permutes k-rows by pi^-1,
// poolfinal/bias re-index by pi^-1 (compile-time). convX folded into gemm1
// (fp32 in, split hi/lo in-register). packW+hist fused. u16 payload.
// 11 dispatches total.

#define THREADS 256

typedef __attribute__((ext_vector_type(8))) short short8v;   // 8 x bf16
typedef __attribute__((ext_vector_type(4))) float f32x4;

__device__ __forceinline__ unsigned short f2bf(float f) {
  union { float f; unsigned u; } v; v.f = f;
  unsigned r = v.u + 0x7FFF + ((v.u >> 16) & 1);   // RNE
  return (unsigned short)(r >> 16);
}
__device__ __forceinline__ float bf2f(unsigned short b) {
  union { unsigned u; float f; } v; v.u = ((unsigned)b) << 16;
  return v.f;
}
__device__ __forceinline__ float bits2f(unsigned u) {
  union { unsigned u; float f; } v; v.u = u;
  return v.f;
}
__device__ __forceinline__ unsigned packbf(float a, float b) {
  return ((unsigned)f2bf(b) << 16) | f2bf(a);
}

// ---------- fused prep: packW (288 blocks) + hist (rest) ----------
// packW: idx=((ks*24+CT)*64+lane)*8+j -> B[kpos][col=CT*16+(lane&15)],
//   kpos = ks*32+(lane>>4)*8+j; layer2 k-row uses true channel
//   c(kpos)=(kpos%6)*16+kpos/6 (A comes pi-permuted from agg3-l1).
__global__ __launch_bounds__(256) void k_prep(
    const float* __restrict__ Wrel1, const float* __restrict__ Wroot1,
    const float* __restrict__ Wrel2, const float* __restrict__ Wroot2,
    unsigned short* __restrict__ PBh, unsigned short* __restrict__ PBl,
    const int* __restrict__ ei, const int* __restrict__ et,
    int* __restrict__ cnt, int* __restrict__ rank, int* __restrict__ bucket,
    int E, int N)
{
  int bid = blockIdx.x;
  if (bid < 288) {
    int lay = bid / 144;
    int idx = (bid % 144) * 256 + threadIdx.x;
    const float* Wroot = lay ? Wroot2 : Wroot1;
    const float* Wrel  = lay ? Wrel2  : Wrel1;
    int j    = idx & 7;
    int lane = (idx >> 3) & 63;
    int CT   = (idx >> 9) % 24;
    int ks   = (idx >> 9) / 24;
    int kpos = ks * 32 + (lane >> 4) * 8 + j;
    int k    = lay ? ((kpos % 6) * 16 + kpos / 6) : kpos;  // pi^-1 for layer 2
    int col  = CT * 16 + (lane & 15);
    int m    = col / 96, jj = col % 96;
    float f  = (m == 0) ? Wroot[k * 96 + jj]
                        : Wrel[((size_t)(m - 1) * 96 + k) * 96 + jj];
    unsigned short h = f2bf(f);
    PBh[(size_t)lay * 36864 + idx] = h;
    PBl[(size_t)lay * 36864 + idx] = f2bf(f - bf2f(h));
  } else {
    int e = (bid - 288) * 256 + threadIdx.x;
    if (e >= E) return;
    int b = et[e] * N + ei[E + e];
    bucket[e] = b;
    rank[e] = atomicAdd(&cnt[b], 1);
  }
}

// ---------- 3-kernel scan over padded bucket counts ----------
__global__ __launch_bounds__(256) void k_scan1(int* __restrict__ data, int* __restrict__ blockSums)
{
  __shared__ int sh[256];
  int tid = threadIdx.x;
  size_t base = (size_t)blockIdx.x * 1024 + (size_t)tid * 4;
  int4 v = *(const int4*)(data + base);
  int i0 = v.x, i1 = i0 + v.y, i2 = i1 + v.z, i3 = i2 + v.w;
  int tsum = i3;
  sh[tid] = tsum;
  __syncthreads();
  for (int off = 1; off < 256; off <<= 1) {
    int t = (tid >= off) ? sh[tid - off] : 0;
    __syncthreads();
    sh[tid] += t;
    __syncthreads();
  }
  int excl = sh[tid] - tsum;
  int4 o; o.x = i0 + excl; o.y = i1 + excl; o.z = i2 + excl; o.w = i3 + excl;
  *(int4*)(data + base) = o;
  if (tid == 255) blockSums[blockIdx.x] = sh[255];
}

__global__ __launch_bounds__(256) void k_scan2(const int* __restrict__ blockSums,
                                               int* __restrict__ blockOffs, int nb)
{
  __shared__ int sh[256];
  int tid = threadIdx.x;
  int v = (tid < nb) ? blockSums[tid] : 0;
  sh[tid] = v;
  __syncthreads();
  for (int off = 1; off < 256; off <<= 1) {
    int t = (tid >= off) ? sh[tid - off] : 0;
    __syncthreads();
    sh[tid] += t;
    __syncthreads();
  }
  blockOffs[tid] = sh[tid] - v;
}

__global__ __launch_bounds__(256) void k_scan3(int* __restrict__ data, const int* __restrict__ blockOffs)
{
  int tid = threadIdx.x;
  size_t base = (size_t)blockIdx.x * 1024 + (size_t)tid * 4;
  int add = blockOffs[blockIdx.x];
  int4 v = *(const int4*)(data + base);
  v.x += add; v.y += add; v.z += add; v.w += add;
  *(int4*)(data + base) = v;
}

// ---------- scatter src ids (u16; N < 65536) ----------
__global__ __launch_bounds__(256) void k_scatter(
    const int* __restrict__ ei, const int* __restrict__ offs,
    const int* __restrict__ rank, const int* __restrict__ bucket,
    unsigned short* __restrict__ payload, int E)
{
  int e = blockIdx.x * THREADS + threadIdx.x;
  if (e >= E) return;
  int b = bucket[e];
  int base = (b == 0) ? 0 : offs[b - 1];
  payload[base + rank[e]] = (unsigned short)ei[e];
}

// ---------- MFMA GEMM: [Yroot fp32 | Hrel bf16](pi-order) = A @ [Wroot|Wrel0..2] ----------
// Block = 64 rows x 384 cols; wave wv owns cols [wv*96, wv*96+96).
// F32IN: A = fp32 x, split hi/lo in-register. Else A = split-bf16 Xh/Xl.
// Epilogue pi-order: lane lr stores its 6 values (ct=0..5) contiguously at
// position lr*6 -> full 384B/192B coalesced rows.
template<bool F32IN>
__global__ __launch_bounds__(256) void k_gemm(
    const void* __restrict__ Xin_, const unsigned short* __restrict__ Xl,
    const unsigned short* __restrict__ PBh, const unsigned short* __restrict__ PBl,
    float* __restrict__ Yroot, unsigned short* __restrict__ Hrel, int nRows)
{
  int wv = threadIdx.x >> 6, lane = threadIdx.x & 63;
  int lr = lane & 15, lq = lane >> 4;
  int r0 = blockIdx.x * 64;

  f32x4 acc[4][6];
#pragma unroll
  for (int rt = 0; rt < 4; ++rt)
#pragma unroll
    for (int ct = 0; ct < 6; ++ct) acc[rt][ct] = (f32x4){0.f, 0.f, 0.f, 0.f};

#pragma unroll 1
  for (int ks = 0; ks < 3; ++ks) {
    short8v Ah[4], Al[4];
#pragma unroll
    for (int rt = 0; rt < 4; ++rt) {
      int row = r0 + rt * 16 + lr;
      if (row >= nRows) row = nRows - 1;          // clamp; stores guarded
      size_t off = (size_t)row * 96 + ks * 32 + lq * 8;
      if (F32IN) {
        const float4* xp = (const float4*)((const float*)Xin_ + off);
        float4 va = xp[0], vb = xp[1];
        float vv[8] = {va.x, va.y, va.z, va.w, vb.x, vb.y, vb.z, vb.w};
#pragma unroll
        for (int j = 0; j < 8; ++j) {
          unsigned short h = f2bf(vv[j]);
          Ah[rt][j] = (short)h;
          Al[rt][j] = (short)f2bf(vv[j] - bf2f(h));
        }
      } else {
        Ah[rt] = *(const short8v*)((const unsigned short*)Xin_ + off);
        Al[rt] = *(const short8v*)(Xl + off);
      }
    }
#pragma unroll
    for (int ct = 0; ct < 6; ++ct) {
      int CT = wv * 6 + ct;
      size_t boff = ((size_t)(ks * 24 + CT) * 64 + lane) * 8;
      short8v Bh = *(const short8v*)(PBh + boff);
      short8v Bl = *(const short8v*)(PBl + boff);
#pragma unroll
      for (int rt = 0; rt < 4; ++rt) {
        acc[rt][ct] = __builtin_amdgcn_mfma_f32_16x16x32_bf16(Ah[rt], Bh, acc[rt][ct], 0, 0, 0);
        acc[rt][ct] = __builtin_amdgcn_mfma_f32_16x16x32_bf16(Al[rt], Bh, acc[rt][ct], 0, 0, 0);
        acc[rt][ct] = __builtin_amdgcn_mfma_f32_16x16x32_bf16(Ah[rt], Bl, acc[rt][ct], 0, 0, 0);
      }
    }
  }

  if (wv == 0) {  // root part, fp32, pi-order: lane lr -> positions lr*6..lr*6+5
#pragma unroll
    for (int rt = 0; rt < 4; ++rt)
#pragma unroll
      for (int q = 0; q < 4; ++q) {
        int row = r0 + rt * 16 + lq * 4 + q;
        if (row < nRows) {
          float2* yp = (float2*)(Yroot + (size_t)row * 96 + lr * 6);
          yp[0] = make_float2(acc[rt][0][q], acc[rt][1][q]);
          yp[1] = make_float2(acc[rt][2][q], acc[rt][3][q]);
          yp[2] = make_float2(acc[rt][4][q], acc[rt][5][q]);
        }
      }
  } else {        // relation part, bf16, pi-order
    int r = wv - 1;
#pragma unroll
    for (int rt = 0; rt < 4; ++rt)
#pragma unroll
      for (int q = 0; q < 4; ++q) {
        int row = r0 + rt * 16 + lq * 4 + q;
        if (row < nRows) {
          unsigned* hp = (unsigned*)(Hrel + ((size_t)r * nRows + row) * 96 + lr * 6);
          hp[0] = packbf(acc[rt][0][q], acc[rt][1][q]);
          hp[1] = packbf(acc[rt][2][q], acc[rt][3][q]);
          hp[2] = packbf(acc[rt][4][q], acc[rt][5][q]);
        }
      }
  }
}

// ---------- aggregate (pi-position space): v = root + bias + sum_r mean_r; relu ----------
// 16 lanes/node; lane l owns positions 6l..6l+5 (true channels l, l+16, ..., l+80).
__global__ __launch_bounds__(256) void k_agg3(
    const float* __restrict__ Yroot, const unsigned short* __restrict__ Hrel,
    const int* __restrict__ offs, const unsigned short* __restrict__ payload,
    const float* __restrict__ bias,
    unsigned int* outH, unsigned int* outL, unsigned int* outF, int N)
{
  int node = blockIdx.x * 16 + (threadIdx.x >> 4);
  int l = threadIdx.x & 15;
  if (node >= N) return;

  const float2* yp = (const float2*)(Yroot + (size_t)node * 96) + 3 * l;
  float2 y0 = yp[0], y1 = yp[1], y2 = yp[2];
  float v[6];
  v[0] = y0.x + bias[l];       v[1] = y0.y + bias[16 + l];   // pi^-1: pos 6l+i -> ch i*16+l
  v[2] = y1.x + bias[32 + l];  v[3] = y1.y + bias[48 + l];
  v[4] = y2.x + bias[64 + l];  v[5] = y2.y + bias[80 + l];

#pragma unroll
  for (int r = 0; r < 3; ++r) {
    int bkt = r * N + node;
    int s = (bkt == 0) ? 0 : offs[bkt - 1];
    int e = offs[bkt];
    const unsigned int* base = (const unsigned int*)(Hrel + (size_t)r * N * 96);
    float a[6] = {0.f, 0.f, 0.f, 0.f, 0.f, 0.f};
    int t = s;
    for (; t + 3 < e; t += 4) {
      int p0 = payload[t], p1 = payload[t + 1], p2 = payload[t + 2], p3 = payload[t + 3];
      const unsigned int* h0 = base + (size_t)p0 * 48 + 3 * l;
      const unsigned int* h1 = base + (size_t)p1 * 48 + 3 * l;
      const unsigned int* h2 = base + (size_t)p2 * 48 + 3 * l;
      const unsigned int* h3 = base + (size_t)p3 * 48 + 3 * l;
      unsigned u0 = h0[0], u1 = h0[1], u2 = h0[2];
      unsigned w0 = h1[0], w1 = h1[1], w2 = h1[2];
      unsigned x0 = h2[0], x1 = h2[1], x2 = h2[2];
      unsigned z0 = h3[0], z1 = h3[1], z2 = h3[2];
      a[0] += bits2f(u0 << 16); a[1] += bits2f(u0 & 0xFFFF0000u);
      a[2] += bits2f(u1 << 16); a[3] += bits2f(u1 & 0xFFFF0000u);
      a[4] += bits2f(u2 << 16); a[5] += bits2f(u2 & 0xFFFF0000u);
      a[0] += bits2f(w0 << 16); a[1] += bits2f(w0 & 0xFFFF0000u);
      a[2] += bits2f(w1 << 16); a[3] += bits2f(w1 & 0xFFFF0000u);
      a[4] += bits2f(w2 << 16); a[5] += bits2f(w2 & 0xFFFF0000u);
      a[0] += bits2f(x0 << 16); a[1] += bits2f(x0 & 0xFFFF0000u);
      a[2] += bits2f(x1 << 16); a[3] += bits2f(x1 & 0xFFFF0000u);
      a[4] += bits2f(x2 << 16); a[5] += bits2f(x2 & 0xFFFF0000u);
      a[0] += bits2f(z0 << 16); a[1] += bits2f(z0 & 0xFFFF0000u);
      a[2] += bits2f(z1 << 16); a[3] += bits2f(z1 & 0xFFFF0000u);
      a[4] += bits2f(z2 << 16); a[5] += bits2f(z2 & 0xFFFF0000u);
    }
    for (; t < e; ++t) {
      const unsigned int* h0 = base + (size_t)payload[t] * 48 + 3 * l;
      unsigned u0 = h0[0], u1 = h0[1], u2 = h0[2];
      a[0] += bits2f(u0 << 16); a[1] += bits2f(u0 & 0xFFFF0000u);
      a[2] += bits2f(u1 << 16); a[3] += bits2f(u1 & 0xFFFF0000u);
      a[4] += bits2f(u2 << 16); a[5] += bits2f(u2 & 0xFFFF0000u);
    }
    float inv = (e > s) ? 1.0f / (float)(e - s) : 0.0f;
#pragma unroll
    for (int i = 0; i < 6; ++i) v[i] += a[i] * inv;
  }
#pragma unroll
  for (int i = 0; i < 6; ++i) v[i] = fmaxf(v[i], 0.f);

  size_t ob = (size_t)node * 48 + 3 * l;
  if (outF) {
    outF[ob]     = packbf(v[0], v[1]);
    outF[ob + 1] = packbf(v[2], v[3]);
    outF[ob + 2] = packbf(v[4], v[5]);
  } else {
    unsigned short h[6], lo[6];
#pragma unroll
    for (int i = 0; i < 6; ++i) { h[i] = f2bf(v[i]); lo[i] = f2bf(v[i] - bf2f(h[i])); }
    outH[ob]     = ((unsigned)h[1] << 16) | h[0];
    outH[ob + 1] = ((unsigned)h[3] << 16) | h[2];
    outH[ob + 2] = ((unsigned)h[5] << 16) | h[4];
    outL[ob]     = ((unsigned)lo[1] << 16) | lo[0];
    outL[ob + 1] = ((unsigned)lo[3] << 16) | lo[2];
    outL[ob + 2] = ((unsigned)lo[5] << 16) | lo[4];
  }
}

// ---------- one block per graph: mean pool (pi-order bf16 rows) + 96->16 linear ----------
__global__ __launch_bounds__(256) void k_poolfinal(
    const unsigned int* __restrict__ H, const int* __restrict__ batch,
    const float* __restrict__ Wlin, const float* __restrict__ blin,
    float* __restrict__ out, int N, int G)
{
  int g = blockIdx.x;
  int tid = threadIdx.x;
  int lo = 0, hi = N;
  while (lo < hi) { int m = (lo + hi) >> 1; if (batch[m] < g) lo = m + 1; else hi = m; }
  int s = lo; hi = N;
  while (lo < hi) { int m = (lo + hi) >> 1; if (batch[m] < g + 1) lo = m + 1; else hi = m; }
  int e = lo;

  int grp = tid >> 4, l = tid & 15;
  float a[6] = {0.f, 0.f, 0.f, 0.f, 0.f, 0.f};
  for (int i = s + grp; i < e; i += 16) {
    const unsigned int* hp = H + (size_t)i * 48 + 3 * l;
    unsigned u0 = hp[0], u1 = hp[1], u2 = hp[2];
    a[0] += bits2f(u0 << 16); a[1] += bits2f(u0 & 0xFFFF0000u);
    a[2] += bits2f(u1 << 16); a[3] += bits2f(u1 & 0xFFFF0000u);
    a[4] += bits2f(u2 << 16); a[5] += bits2f(u2 & 0xFFFF0000u);
  }
  __shared__ float sh[16][96];
  __shared__ float pooled[96];
#pragma unroll
  for (int i = 0; i < 6; ++i) sh[grp][6 * l + i] = a[i];
  __syncthreads();
  if (tid < 96) {
    float t = 0.f;
#pragma unroll
    for (int j = 0; j < 16; ++j) t += sh[j][tid];
    float inv = (e > s) ? 1.0f / (float)(e - s) : 0.0f;
    pooled[tid] = t * inv;
  }
  __syncthreads();
  if (tid < 16) {
    float acc = blin[tid];
#pragma unroll
    for (int k = 0; k < 96; ++k)   // pooled pos k = true channel (k%6)*16+k/6
      acc = fmaf(pooled[k], Wlin[((k % 6) * 16 + k / 6) * 16 + tid], acc);
    out[(size_t)g * 16 + tid] = acc;
  }
}

extern "C" void kernel_launch(void* const* d_in, const int* in_sizes, int n_in,
                              void* d_out, int out_size, void* d_ws, size_t ws_size,
                              hipStream_t stream)
{
  const float* x      = (const float*)d_in[0];
  const int*   ei     = (const int*)d_in[1];
  const int*   et     = (const int*)d_in[2];
  const int*   batch  = (const int*)d_in[3];
  const float* Wrel1  = (const float*)d_in[4];
  const float* Wroot1 = (const float*)d_in[5];
  const float* b1     = (const float*)d_in[6];
  const float* Wrel2  = (const float*)d_in[7];
  const float* Wroot2 = (const float*)d_in[8];
  const float* b2     = (const float*)d_in[9];
  const float* Wlin   = (const float*)d_in[10];
  const float* blin   = (const float*)d_in[11];
  float* out = (float*)d_out;
  (void)n_in; (void)ws_size;

  int N = in_sizes[0] / 96;   // 50000 (< 65536: u16 payload assumption)
  int E = in_sizes[1] / 2;
  int G = out_size / 16;
  int NB = 3 * N;
  int nb1 = (NB + 1023) / 1024;
  int SCAN = nb1 * 1024;

  char* w = (char*)d_ws;
  size_t o = 0;
  auto carve = [&](size_t bytes) -> char* {
    char* p = w + o;
    o = (o + bytes + 255) & ~(size_t)255;
    return p;
  };
  float*          Yroot = (float*)carve((size_t)N * 96 * 4);                 // 19.2 MB
  unsigned short* Hrel  = (unsigned short*)carve((size_t)3 * N * 96 * 2);    // 28.8 MB
  unsigned short* Xh    = (unsigned short*)carve((size_t)N * 96 * 2);        // 9.6 MB
  unsigned short* Xl    = (unsigned short*)carve((size_t)N * 96 * 2);        // 9.6 MB
  unsigned short* Hout  = (unsigned short*)carve((size_t)N * 96 * 2);        // 9.6 MB
  unsigned short* PBh   = (unsigned short*)carve((size_t)2 * 36864 * 2);
  unsigned short* PBl   = (unsigned short*)carve((size_t)2 * 36864 * 2);
  int*            offs  = (int*)carve((size_t)SCAN * 4);
  int*            blockSums = (int*)carve(256 * 4);
  int*            blockOffs = (int*)carve(256 * 4);
  int*            rank  = (int*)carve((size_t)E * 4);
  int*            bucket= (int*)carve((size_t)E * 4);
  unsigned short* payload = (unsigned short*)carve((size_t)E * 2);

  hipMemsetAsync(offs, 0, (size_t)SCAN * 4, stream);

  int histBlocks = (E + THREADS - 1) / THREADS;
  k_prep<<<288 + histBlocks, THREADS, 0, stream>>>(
      Wrel1, Wroot1, Wrel2, Wroot2, PBh, PBl, ei, et, offs, rank, bucket, E, N);
  k_scan1<<<nb1, THREADS, 0, stream>>>(offs, blockSums);
  k_scan2<<<1, THREADS, 0, stream>>>(blockSums, blockOffs, nb1);
  k_scan3<<<nb1, THREADS, 0, stream>>>(offs, blockOffs);
  k_scatter<<<histBlocks, THREADS, 0, stream>>>(ei, offs, rank, bucket, payload, E);

  int gg = (N + 63) / 64;
  int ag = (N + 15) / 16;

  // layer 1 (fp32 input, in-register hi/lo split)
  k_gemm<true><<<gg, THREADS, 0, stream>>>(x, nullptr, PBh, PBl, Yroot, Hrel, N);
  k_agg3<<<ag, THREADS, 0, stream>>>(Yroot, Hrel, offs, payload, b1,
                                     (unsigned int*)Xh, (unsigned int*)Xl, nullptr, N);
  // layer 2 (split-bf16 input from agg3)
  k_gemm<false><<<gg, THREADS, 0, stream>>>(Xh, Xl, PBh + 36864, PBl + 36864, Yroot, Hrel, N);
  k_agg3<<<ag, THREADS, 0, stream>>>(Yroot, Hrel, offs, payload, b2,
                                     nullptr, nullptr, (unsigned int*)Hout, N);

  k_poolfinal<<<G, THREADS, 0, stream>>>((const unsigned int*)Hout, batch, Wlin, blin, out, N, G);
}

// Round 8
// 268.144 us; speedup vs baseline: 7.5565x; 1.0894x over previous
//
#include <hip/hip_runtime.h>

// RGCN 2-layer + mean-pool + linear, MI355X (gfx950).
// r7 (resubmit; prior round hit GPU-acquisition timeout, never measured):
// k_gemm rebuilt for occupancy — r6 sat at VGPR=136 (just past the 128
// cliff -> 2 waves/SIMD, 75% stall, MfmaUtil 9%). Now: 32-row blocks (rt=2,
// acc 48 VGPR), 2-stage A-prefetch, __launch_bounds__(256,4) pinning <=128
// VGPR -> 4 waves/SIMD, 1563 blocks. pi-permuted epilogue unchanged.

#define THREADS 256

typedef __attribute__((ext_vector_type(8))) short short8v;   // 8 x bf16
typedef __attribute__((ext_vector_type(4))) float f32x4;

__device__ __forceinline__ unsigned short f2bf(float f) {
  union { float f; unsigned u; } v; v.f = f;
  unsigned r = v.u + 0x7FFF + ((v.u >> 16) & 1);   // RNE
  return (unsigned short)(r >> 16);
}
__device__ __forceinline__ float bf2f(unsigned short b) {
  union { unsigned u; float f; } v; v.u = ((unsigned)b) << 16;
  return v.f;
}
__device__ __forceinline__ float bits2f(unsigned u) {
  union { unsigned u; float f; } v; v.u = u;
  return v.f;
}
__device__ __forceinline__ unsigned packbf(float a, float b) {
  return ((unsigned)f2bf(b) << 16) | f2bf(a);
}

// ---------- fused prep: packW (288 blocks) + hist (rest) ----------
__global__ __launch_bounds__(256) void k_prep(
    const float* __restrict__ Wrel1, const float* __restrict__ Wroot1,
    const float* __restrict__ Wrel2, const float* __restrict__ Wroot2,
    unsigned short* __restrict__ PBh, unsigned short* __restrict__ PBl,
    const int* __restrict__ ei, const int* __restrict__ et,
    int* __restrict__ cnt, int* __restrict__ rank, int* __restrict__ bucket,
    int E, int N)
{
  int bid = blockIdx.x;
  if (bid < 288) {
    int lay = bid / 144;
    int idx = (bid % 144) * 256 + threadIdx.x;
    const float* Wroot = lay ? Wroot2 : Wroot1;
    const float* Wrel  = lay ? Wrel2  : Wrel1;
    int j    = idx & 7;
    int lane = (idx >> 3) & 63;
    int CT   = (idx >> 9) % 24;
    int ks   = (idx >> 9) / 24;
    int kpos = ks * 32 + (lane >> 4) * 8 + j;
    int k    = lay ? ((kpos % 6) * 16 + kpos / 6) : kpos;  // pi^-1 for layer 2
    int col  = CT * 16 + (lane & 15);
    int m    = col / 96, jj = col % 96;
    float f  = (m == 0) ? Wroot[k * 96 + jj]
                        : Wrel[((size_t)(m - 1) * 96 + k) * 96 + jj];
    unsigned short h = f2bf(f);
    PBh[(size_t)lay * 36864 + idx] = h;
    PBl[(size_t)lay * 36864 + idx] = f2bf(f - bf2f(h));
  } else {
    int e = (bid - 288) * 256 + threadIdx.x;
    if (e >= E) return;
    int b = et[e] * N + ei[E + e];
    bucket[e] = b;
    rank[e] = atomicAdd(&cnt[b], 1);
  }
}

// ---------- 3-kernel scan over padded bucket counts ----------
__global__ __launch_bounds__(256) void k_scan1(int* __restrict__ data, int* __restrict__ blockSums)
{
  __shared__ int sh[256];
  int tid = threadIdx.x;
  size_t base = (size_t)blockIdx.x * 1024 + (size_t)tid * 4;
  int4 v = *(const int4*)(data + base);
  int i0 = v.x, i1 = i0 + v.y, i2 = i1 + v.z, i3 = i2 + v.w;
  int tsum = i3;
  sh[tid] = tsum;
  __syncthreads();
  for (int off = 1; off < 256; off <<= 1) {
    int t = (tid >= off) ? sh[tid - off] : 0;
    __syncthreads();
    sh[tid] += t;
    __syncthreads();
  }
  int excl = sh[tid] - tsum;
  int4 o; o.x = i0 + excl; o.y = i1 + excl; o.z = i2 + excl; o.w = i3 + excl;
  *(int4*)(data + base) = o;
  if (tid == 255) blockSums[blockIdx.x] = sh[255];
}

__global__ __launch_bounds__(256) void k_scan2(const int* __restrict__ blockSums,
                                               int* __restrict__ blockOffs, int nb)
{
  __shared__ int sh[256];
  int tid = threadIdx.x;
  int v = (tid < nb) ? blockSums[tid] : 0;
  sh[tid] = v;
  __syncthreads();
  for (int off = 1; off < 256; off <<= 1) {
    int t = (tid >= off) ? sh[tid - off] : 0;
    __syncthreads();
    sh[tid] += t;
    __syncthreads();
  }
  blockOffs[tid] = sh[tid] - v;
}

__global__ __launch_bounds__(256) void k_scan3(int* __restrict__ data, const int* __restrict__ blockOffs)
{
  int tid = threadIdx.x;
  size_t base = (size_t)blockIdx.x * 1024 + (size_t)tid * 4;
  int add = blockOffs[blockIdx.x];
  int4 v = *(const int4*)(data + base);
  v.x += add; v.y += add; v.z += add; v.w += add;
  *(int4*)(data + base) = v;
}

// ---------- scatter src ids (u16; N < 65536) ----------
__global__ __launch_bounds__(256) void k_scatter(
    const int* __restrict__ ei, const int* __restrict__ offs,
    const int* __restrict__ rank, const int* __restrict__ bucket,
    unsigned short* __restrict__ payload, int E)
{
  int e = blockIdx.x * THREADS + threadIdx.x;
  if (e >= E) return;
  int b = bucket[e];
  int base = (b == 0) ? 0 : offs[b - 1];
  payload[base + rank[e]] = (unsigned short)ei[e];
}

// ---------- MFMA GEMM: [Yroot fp32 | Hrel bf16](pi-order) = A @ [Wroot|Wrel0..2] ----------
// Block = 32 rows x 384 cols; wave wv owns cols [wv*96, wv*96+96).
// 2-stage A prefetch (ks+1 issued during ks compute); F32IN keeps raw float4s
// and converts at use so the prefetch isn't serialized by the split.
template<bool F32IN>
__global__ __launch_bounds__(256, 4) void k_gemm(
    const void* __restrict__ Xin_, const unsigned short* __restrict__ Xl,
    const unsigned short* __restrict__ PBh, const unsigned short* __restrict__ PBl,
    float* __restrict__ Yroot, unsigned short* __restrict__ Hrel, int nRows)
{
  const float* Xf          = (const float*)Xin_;
  const unsigned short* Xh = (const unsigned short*)Xin_;
  int wv = threadIdx.x >> 6, lane = threadIdx.x & 63;
  int lr = lane & 15, lq = lane >> 4;
  int r0 = blockIdx.x * 32;

  size_t aoff[2];
#pragma unroll
  for (int rt = 0; rt < 2; ++rt) {
    int row = r0 + rt * 16 + lr;
    if (row >= nRows) row = nRows - 1;          // clamp; stores guarded
    aoff[rt] = (size_t)row * 96 + lq * 8;
  }

  f32x4 acc[2][6];
#pragma unroll
  for (int rt = 0; rt < 2; ++rt)
#pragma unroll
    for (int ct = 0; ct < 6; ++ct) acc[rt][ct] = (f32x4){0.f, 0.f, 0.f, 0.f};

  float4 fa[2], fb[2], nfa[2], nfb[2];
  short8v Ah[2], Al[2], nAh[2], nAl[2];

  // issue ks=0 loads
#pragma unroll
  for (int rt = 0; rt < 2; ++rt) {
    if (F32IN) {
      fa[rt] = *(const float4*)(Xf + aoff[rt]);
      fb[rt] = *(const float4*)(Xf + aoff[rt] + 4);
    } else {
      Ah[rt] = *(const short8v*)(Xh + aoff[rt]);
      Al[rt] = *(const short8v*)(Xl + aoff[rt]);
    }
  }

#pragma unroll
  for (int ks = 0; ks < 3; ++ks) {
    // prefetch ks+1
    if (ks < 2) {
#pragma unroll
      for (int rt = 0; rt < 2; ++rt) {
        size_t off = aoff[rt] + (ks + 1) * 32;
        if (F32IN) {
          nfa[rt] = *(const float4*)(Xf + off);
          nfb[rt] = *(const float4*)(Xf + off + 4);
        } else {
          nAh[rt] = *(const short8v*)(Xh + off);
          nAl[rt] = *(const short8v*)(Xl + off);
        }
      }
    }
    if (F32IN) {  // convert current raw floats -> split bf16
#pragma unroll
      for (int rt = 0; rt < 2; ++rt) {
        float vv[8] = {fa[rt].x, fa[rt].y, fa[rt].z, fa[rt].w,
                       fb[rt].x, fb[rt].y, fb[rt].z, fb[rt].w};
#pragma unroll
        for (int j = 0; j < 8; ++j) {
          unsigned short h = f2bf(vv[j]);
          Ah[rt][j] = (short)h;
          Al[rt][j] = (short)f2bf(vv[j] - bf2f(h));
        }
      }
    }
#pragma unroll
    for (int ct = 0; ct < 6; ++ct) {
      int CT = wv * 6 + ct;
      size_t boff = ((size_t)(ks * 24 + CT) * 64 + lane) * 8;
      short8v Bh = *(const short8v*)(PBh + boff);
      short8v Bl = *(const short8v*)(PBl + boff);
#pragma unroll
      for (int rt = 0; rt < 2; ++rt) {
        acc[rt][ct] = __builtin_amdgcn_mfma_f32_16x16x32_bf16(Ah[rt], Bh, acc[rt][ct], 0, 0, 0);
        acc[rt][ct] = __builtin_amdgcn_mfma_f32_16x16x32_bf16(Al[rt], Bh, acc[rt][ct], 0, 0, 0);
        acc[rt][ct] = __builtin_amdgcn_mfma_f32_16x16x32_bf16(Ah[rt], Bl, acc[rt][ct], 0, 0, 0);
      }
    }
    // rotate prefetch into current (renamed away by unroll)
    if (ks < 2) {
#pragma unroll
      for (int rt = 0; rt < 2; ++rt) {
        if (F32IN) { fa[rt] = nfa[rt]; fb[rt] = nfb[rt]; }
        else       { Ah[rt] = nAh[rt]; Al[rt] = nAl[rt]; }
      }
    }
  }

  if (wv == 0) {  // root part, fp32, pi-order: lane lr -> positions lr*6..lr*6+5
#pragma unroll
    for (int rt = 0; rt < 2; ++rt)
#pragma unroll
      for (int q = 0; q < 4; ++q) {
        int row = r0 + rt * 16 + lq * 4 + q;
        if (row < nRows) {
          float2* yp = (float2*)(Yroot + (size_t)row * 96 + lr * 6);
          yp[0] = make_float2(acc[rt][0][q], acc[rt][1][q]);
          yp[1] = make_float2(acc[rt][2][q], acc[rt][3][q]);
          yp[2] = make_float2(acc[rt][4][q], acc[rt][5][q]);
        }
      }
  } else {        // relation part, bf16, pi-order
    int r = wv - 1;
#pragma unroll
    for (int rt = 0; rt < 2; ++rt)
#pragma unroll
      for (int q = 0; q < 4; ++q) {
        int row = r0 + rt * 16 + lq * 4 + q;
        if (row < nRows) {
          unsigned* hp = (unsigned*)(Hrel + ((size_t)r * nRows + row) * 96 + lr * 6);
          hp[0] = packbf(acc[rt][0][q], acc[rt][1][q]);
          hp[1] = packbf(acc[rt][2][q], acc[rt][3][q]);
          hp[2] = packbf(acc[rt][4][q], acc[rt][5][q]);
        }
      }
  }
}

// ---------- aggregate (pi-position space): v = root + bias + sum_r mean_r; relu ----------
__global__ __launch_bounds__(256) void k_agg3(
    const float* __restrict__ Yroot, const unsigned short* __restrict__ Hrel,
    const int* __restrict__ offs, const unsigned short* __restrict__ payload,
    const float* __restrict__ bias,
    unsigned int* outH, unsigned int* outL, unsigned int* outF, int N)
{
  int node = blockIdx.x * 16 + (threadIdx.x >> 4);
  int l = threadIdx.x & 15;
  if (node >= N) return;

  const float2* yp = (const float2*)(Yroot + (size_t)node * 96) + 3 * l;
  float2 y0 = yp[0], y1 = yp[1], y2 = yp[2];
  float v[6];
  v[0] = y0.x + bias[l];       v[1] = y0.y + bias[16 + l];   // pi^-1: pos 6l+i -> ch i*16+l
  v[2] = y1.x + bias[32 + l];  v[3] = y1.y + bias[48 + l];
  v[4] = y2.x + bias[64 + l];  v[5] = y2.y + bias[80 + l];

#pragma unroll
  for (int r = 0; r < 3; ++r) {
    int bkt = r * N + node;
    int s = (bkt == 0) ? 0 : offs[bkt - 1];
    int e = offs[bkt];
    const unsigned int* base = (const unsigned int*)(Hrel + (size_t)r * N * 96);
    float a[6] = {0.f, 0.f, 0.f, 0.f, 0.f, 0.f};
    int t = s;
    for (; t + 3 < e; t += 4) {
      int p0 = payload[t], p1 = payload[t + 1], p2 = payload[t + 2], p3 = payload[t + 3];
      const unsigned int* h0 = base + (size_t)p0 * 48 + 3 * l;
      const unsigned int* h1 = base + (size_t)p1 * 48 + 3 * l;
      const unsigned int* h2 = base + (size_t)p2 * 48 + 3 * l;
      const unsigned int* h3 = base + (size_t)p3 * 48 + 3 * l;
      unsigned u0 = h0[0], u1 = h0[1], u2 = h0[2];
      unsigned w0 = h1[0], w1 = h1[1], w2 = h1[2];
      unsigned x0 = h2[0], x1 = h2[1], x2 = h2[2];
      unsigned z0 = h3[0], z1 = h3[1], z2 = h3[2];
      a[0] += bits2f(u0 << 16); a[1] += bits2f(u0 & 0xFFFF0000u);
      a[2] += bits2f(u1 << 16); a[3] += bits2f(u1 & 0xFFFF0000u);
      a[4] += bits2f(u2 << 16); a[5] += bits2f(u2 & 0xFFFF0000u);
      a[0] += bits2f(w0 << 16); a[1] += bits2f(w0 & 0xFFFF0000u);
      a[2] += bits2f(w1 << 16); a[3] += bits2f(w1 & 0xFFFF0000u);
      a[4] += bits2f(w2 << 16); a[5] += bits2f(w2 & 0xFFFF0000u);
      a[0] += bits2f(x0 << 16); a[1] += bits2f(x0 & 0xFFFF0000u);
      a[2] += bits2f(x1 << 16); a[3] += bits2f(x1 & 0xFFFF0000u);
      a[4] += bits2f(x2 << 16); a[5] += bits2f(x2 & 0xFFFF0000u);
      a[0] += bits2f(z0 << 16); a[1] += bits2f(z0 & 0xFFFF0000u);
      a[2] += bits2f(z1 << 16); a[3] += bits2f(z1 & 0xFFFF0000u);
      a[4] += bits2f(z2 << 16); a[5] += bits2f(z2 & 0xFFFF0000u);
    }
    for (; t < e; ++t) {
      const unsigned int* h0 = base + (size_t)payload[t] * 48 + 3 * l;
      unsigned u0 = h0[0], u1 = h0[1], u2 = h0[2];
      a[0] += bits2f(u0 << 16); a[1] += bits2f(u0 & 0xFFFF0000u);
      a[2] += bits2f(u1 << 16); a[3] += bits2f(u1 & 0xFFFF0000u);
      a[4] += bits2f(u2 << 16); a[5] += bits2f(u2 & 0xFFFF0000u);
    }
    float inv = (e > s) ? 1.0f / (float)(e - s) : 0.0f;
#pragma unroll
    for (int i = 0; i < 6; ++i) v[i] += a[i] * inv;
  }
#pragma unroll
  for (int i = 0; i < 6; ++i) v[i] = fmaxf(v[i], 0.f);

  size_t ob = (size_t)node * 48 + 3 * l;
  if (outF) {
    outF[ob]     = packbf(v[0], v[1]);
    outF[ob + 1] = packbf(v[2], v[3]);
    outF[ob + 2] = packbf(v[4], v[5]);
  } else {
    unsigned short h[6], lo[6];
#pragma unroll
    for (int i = 0; i < 6; ++i) { h[i] = f2bf(v[i]); lo[i] = f2bf(v[i] - bf2f(h[i])); }
    outH[ob]     = ((unsigned)h[1] << 16) | h[0];
    outH[ob + 1] = ((unsigned)h[3] << 16) | h[2];
    outH[ob + 2] = ((unsigned)h[5] << 16) | h[4];
    outL[ob]     = ((unsigned)lo[1] << 16) | lo[0];
    outL[ob + 1] = ((unsigned)lo[3] << 16) | lo[2];
    outL[ob + 2] = ((unsigned)lo[5] << 16) | lo[4];
  }
}

// ---------- one block per graph: mean pool (pi-order bf16 rows) + 96->16 linear ----------
__global__ __launch_bounds__(256) void k_poolfinal(
    const unsigned int* __restrict__ H, const int* __restrict__ batch,
    const float* __restrict__ Wlin, const float* __restrict__ blin,
    float* __restrict__ out, int N, int G)
{
  int g = blockIdx.x;
  int tid = threadIdx.x;
  int lo = 0, hi = N;
  while (lo < hi) { int m = (lo + hi) >> 1; if (batch[m] < g) lo = m + 1; else hi = m; }
  int s = lo; hi = N;
  while (lo < hi) { int m = (lo + hi) >> 1; if (batch[m] < g + 1) lo = m + 1; else hi = m; }
  int e = lo;

  int grp = tid >> 4, l = tid & 15;
  float a[6] = {0.f, 0.f, 0.f, 0.f, 0.f, 0.f};
  for (int i = s + grp; i < e; i += 16) {
    const unsigned int* hp = H + (size_t)i * 48 + 3 * l;
    unsigned u0 = hp[0], u1 = hp[1], u2 = hp[2];
    a[0] += bits2f(u0 << 16); a[1] += bits2f(u0 & 0xFFFF0000u);
    a[2] += bits2f(u1 << 16); a[3] += bits2f(u1 & 0xFFFF0000u);
    a[4] += bits2f(u2 << 16); a[5] += bits2f(u2 & 0xFFFF0000u);
  }
  __shared__ float sh[16][96];
  __shared__ float pooled[96];
#pragma unroll
  for (int i = 0; i < 6; ++i) sh[grp][6 * l + i] = a[i];
  __syncthreads();
  if (tid < 96) {
    float t = 0.f;
#pragma unroll
    for (int j = 0; j < 16; ++j) t += sh[j][tid];
    float inv = (e > s) ? 1.0f / (float)(e - s) : 0.0f;
    pooled[tid] = t * inv;
  }
  __syncthreads();
  if (tid < 16) {
    float acc = blin[tid];
#pragma unroll
    for (int k = 0; k < 96; ++k)   // pooled pos k = true channel (k%6)*16+k/6
      acc = fmaf(pooled[k], Wlin[((k % 6) * 16 + k / 6) * 16 + tid], acc);
    out[(size_t)g * 16 + tid] = acc;
  }
}

extern "C" void kernel_launch(void* const* d_in, const int* in_sizes, int n_in,
                              void* d_out, int out_size, void* d_ws, size_t ws_size,
                              hipStream_t stream)
{
  const float* x      = (const float*)d_in[0];
  const int*   ei     = (const int*)d_in[1];
  const int*   et     = (const int*)d_in[2];
  const int*   batch  = (const int*)d_in[3];
  const float* Wrel1  = (const float*)d_in[4];
  const float* Wroot1 = (const float*)d_in[5];
  const float* b1     = (const float*)d_in[6];
  const float* Wrel2  = (const float*)d_in[7];
  const float* Wroot2 = (const float*)d_in[8];
  const float* b2     = (const float*)d_in[9];
  const float* Wlin   = (const float*)d_in[10];
  const float* blin   = (const float*)d_in[11];
  float* out = (float*)d_out;
  (void)n_in; (void)ws_size;

  int N = in_sizes[0] / 96;   // 50000 (< 65536: u16 payload assumption)
  int E = in_sizes[1] / 2;
  int G = out_size / 16;
  int NB = 3 * N;
  int nb1 = (NB + 1023) / 1024;
  int SCAN = nb1 * 1024;

  char* w = (char*)d_ws;
  size_t o = 0;
  auto carve = [&](size_t bytes) -> char* {
    char* p = w + o;
    o = (o + bytes + 255) & ~(size_t)255;
    return p;
  };
  float*          Yroot = (float*)carve((size_t)N * 96 * 4);                 // 19.2 MB
  unsigned short* Hrel  = (unsigned short*)carve((size_t)3 * N * 96 * 2);    // 28.8 MB
  unsigned short* Xh    = (unsigned short*)carve((size_t)N * 96 * 2);        // 9.6 MB
  unsigned short* Xl    = (unsigned short*)carve((size_t)N * 96 * 2);        // 9.6 MB
  unsigned short* Hout  = (unsigned short*)carve((size_t)N * 96 * 2);        // 9.6 MB
  unsigned short* PBh   = (unsigned short*)carve((size_t)2 * 36864 * 2);
  unsigned short* PBl   = (unsigned short*)carve((size_t)2 * 36864 * 2);
  int*            offs  = (int*)carve((size_t)SCAN * 4);
  int*            blockSums = (int*)carve(256 * 4);
  int*            blockOffs = (int*)carve(256 * 4);
  int*            rank  = (int*)carve((size_t)E * 4);
  int*            bucket= (int*)carve((size_t)E * 4);
  unsigned short* payload = (unsigned short*)carve((size_t)E * 2);

  hipMemsetAsync(offs, 0, (size_t)SCAN * 4, stream);

  int histBlocks = (E + THREADS - 1) / THREADS;
  k_prep<<<288 + histBlocks, THREADS, 0, stream>>>(
      Wrel1, Wroot1, Wrel2, Wroot2, PBh, PBl, ei, et, offs, rank, bucket, E, N);
  k_scan1<<<nb1, THREADS, 0, stream>>>(offs, blockSums);
  k_scan2<<<1, THREADS, 0, stream>>>(blockSums, blockOffs, nb1);
  k_scan3<<<nb1, THREADS, 0, stream>>>(offs, blockOffs);
  k_scatter<<<histBlocks, THREADS, 0, stream>>>(ei, offs, rank, bucket, payload, E);

  int gg = (N + 31) / 32;
  int ag = (N + 15) / 16;

  // layer 1 (fp32 input, in-register hi/lo split)
  k_gemm<true><<<gg, THREADS, 0, stream>>>(x, nullptr, PBh, PBl, Yroot, Hrel, N);
  k_agg3<<<ag, THREADS, 0, stream>>>(Yroot, Hrel, offs, payload, b1,
                                     (unsigned int*)Xh, (unsigned int*)Xl, nullptr, N);
  // layer 2 (split-bf16 input from agg3)
  k_gemm<false><<<gg, THREADS, 0, stream>>>(Xh, Xl, PBh + 36864, PBl + 36864, Yroot, Hrel, N);
  k_agg3<<<ag, THREADS, 0, stream>>>(Yroot, Hrel, offs, payload, b2,
                                     nullptr, nullptr, (unsigned int*)Hout, N);

  k_poolfinal<<<G, THREADS, 0, stream>>>((const unsigned int*)Hout, batch, Wlin, blin, out, N, G);
}